// Round 19
// baseline (656.927 us; speedup 1.0000x reference)
//
#include <hip/hip_runtime.h>
#include <hip/hip_bf16.h>
#include <math.h>

#define E 256
#define Hh 8
#define DH 32
#define NP 1728
#define PP3 125
#define Bb 4
#define NUM_MASKC 1296
#define NKEEP 432
#define LE 4
#define LD 2
#define NC 40

typedef __attribute__((ext_vector_type(4))) float f32x4;
typedef __attribute__((ext_vector_type(8))) short bf16x8;
typedef __attribute__((ext_vector_type(4))) short s16x4;

#define QSCALE 0.25505654708402214f   /* (1/sqrt(32)) * log2(e) */

__device__ inline short f2b(float f) {
    __hip_bfloat16 h = __float2bfloat16(f);   // HW RNE cvt
    return *reinterpret_cast<short*>(&h);
}
__device__ inline float b2f(short s) {
    union { unsigned u; float f; } v; v.u = ((unsigned)(unsigned short)s) << 16;
    return v.f;
}
__device__ inline unsigned cvt_pk(float lo, float hi) {
    unsigned r;
    asm("v_cvt_pk_bf16_f32 %0, %1, %2" : "=v"(r) : "v"(lo), "v"(hi));
    return r;
}
__device__ inline void gl_lds16(const void* g, void* l) {
    __builtin_amdgcn_global_load_lds(
        (const __attribute__((address_space(1))) void*)g,
        (__attribute__((address_space(3))) void*)l, 16, 0, 0);
}

// ---- one-shot fp32 -> bf16 weight conversion (25 matrices, zero-padded) ----
struct W2B { const float* src; short* dst; int n; int npad; };
struct W2BTab { W2B e[25]; };
__global__ void k_w2b(W2BTab tab) {
    W2B w = tab.e[blockIdx.y];
    int i = (blockIdx.x*256 + threadIdx.x) * 8;
    if (i + 8 <= w.n) {
        float4 a = *(const float4*)(w.src + i);
        float4 b = *(const float4*)(w.src + i + 4);
        short t[8] = {f2b(a.x),f2b(a.y),f2b(a.z),f2b(a.w),
                      f2b(b.x),f2b(b.y),f2b(b.z),f2b(b.w)};
        *(bf16x8*)(w.dst + i) = *(const bf16x8*)t;
    } else if (i < w.npad) {
        *(bf16x8*)(w.dst + i) = (bf16x8)0;
    }
}

// ---- stable rank == jnp.argsort: 7 blocks per batch row, noise in LDS ----
__global__ void k_rank(const float* __restrict__ noise, int* __restrict__ shuf,
                       int* __restrict__ keep_pos, float* __restrict__ out_mask)
{
    __shared__ float ns[NP];
    int b = blockIdx.x / 7, it = blockIdx.x % 7;
    const float* nr = noise + (size_t)b*NP;
    int tid = threadIdx.x;
    for (int j = tid; j < NP; j += 256) ns[j] = nr[j];
    __syncthreads();
    int i = it*256 + tid;
    if (i < NP) {
        float ni = ns[i];
        int rank = 0;
        for (int j = 0; j < NP; ++j) {
            float nj = ns[j];
            rank += (nj < ni) || (nj == ni && j < i);
        }
        shuf[b*NP + rank] = i;
        keep_pos[b*NP + i] = (rank >= NUM_MASKC) ? (rank - NUM_MASKC) : -1;
        out_mask[b*NP + i] = (rank < NUM_MASKC) ? 1.0f : 0.0f;
    }
}

// ---- xg output only ----
__global__ void k_xg(const float* __restrict__ x, float* __restrict__ out_xg)
{
    int bn = blockIdx.x;            // b*NP + n
    int b = bn / NP, n = bn % NP;
    int a0 = n / 144, r = n % 144, b0 = r / 12, c0 = r % 12;
    int t = threadIdx.x;
    if (t < PP3) {
        int pa = t / 25, rem = t % 25, pbq = rem / 5, pc = rem % 5;
        out_xg[(size_t)bn*PP3 + t] =
            x[(size_t)b*216000 + (size_t)(a0*5+pa)*3600 + (b0*5+pbq)*60 + (c0*5+pc)];
    }
}

// ---- patch extract + embed for VISIBLE tokens only (bf16 out) ----
__global__ void k_patch_vis(const float* __restrict__ x, const float* __restrict__ pw,
                            const float* __restrict__ pb, const float* __restrict__ pos,
                            const int* __restrict__ shuf, short* __restrict__ visb)
{
    int row = blockIdx.x;            // b*NKEEP + s
    int b = row / NKEEP, s = row % NKEEP;
    int n = shuf[b*NP + NUM_MASKC + s];
    int a0 = n / 144, r = n % 144, b0 = r / 12, c0 = r % 12;
    __shared__ float patch[PP3];
    int t = threadIdx.x;
    if (t < PP3) {
        int pa = t / 25, rem = t % 25, pbq = rem / 5, pc = rem % 5;
        patch[t] = x[(size_t)b*216000 + (size_t)(a0*5+pa)*3600 + (b0*5+pbq)*60 + (c0*5+pc)];
    }
    __syncthreads();
    float acc = pb[t] + pos[(size_t)n*E + t];
    const float* w = pw + (size_t)t*PP3;
    for (int k = 0; k < PP3; ++k) acc += patch[k] * w[k];
    visb[(size_t)row*E + t] = f2b(acc);
}

// ---- bf16 MFMA GEMM 64x64, global_load_lds + XOR swizzle (round-17 form) ----
// out modes: qkvb!=null -> qkv split ; else Cb!=null -> bf16 C ; else fp32 Cf.
__global__ __launch_bounds__(256) void
k_mgemm(const short* __restrict__ A, const short* __restrict__ W,
        const float* __restrict__ bias, float* __restrict__ Cf,
        short* __restrict__ Cb, int M, int N, int K, int act,
        short* __restrict__ qkvb, short* __restrict__ vTb, int S)
{
    __shared__ short As[64][64];   // 16B chunk c of row r holds global chunk c^(r&7)
    __shared__ short Ws[64][64];
    int tid = threadIdx.x;
    int lane = tid & 63, wave = tid >> 6;
    int rb = blockIdx.y * 64, cb = blockIdx.x * 64;
    int wr = (wave >> 1) * 32, wc = (wave & 1) * 32;
    int fr = lane & 15, fq = lane >> 4;
    f32x4 acc[2][2];
    #pragma unroll
    for (int m = 0; m < 2; ++m)
        #pragma unroll
        for (int n = 0; n < 2; ++n) acc[m][n] = (f32x4)0.f;
    int rl = lane >> 3, cl = lane & 7;
    int r0 = 16 * wave;
    for (int kk0 = 0; kk0 < K; kk0 += 64) {
        #pragma unroll
        for (int j = 0; j < 2; ++j) {
            int r = r0 + 8*j + rl;
            int cs = cl ^ (r & 7);
            gl_lds16(A + (size_t)(rb + r)*K + kk0 + cs*8, &As[r0 + 8*j][0]);
            gl_lds16(W + (size_t)(cb + r)*K + kk0 + cs*8, &Ws[r0 + 8*j][0]);
        }
        __syncthreads();
        #pragma unroll
        for (int t = 0; t < 2; ++t) {
            int rA0 = wr + fr, rA1 = wr + 16 + fr;
            int rB0 = wc + fr, rB1 = wc + 16 + fr;
            bf16x8 a0 = *(const bf16x8*)&As[rA0][(((4*t + fq) ^ (rA0 & 7)) << 3)];
            bf16x8 a1 = *(const bf16x8*)&As[rA1][(((4*t + fq) ^ (rA1 & 7)) << 3)];
            bf16x8 b0 = *(const bf16x8*)&Ws[rB0][(((4*t + fq) ^ (rB0 & 7)) << 3)];
            bf16x8 b1 = *(const bf16x8*)&Ws[rB1][(((4*t + fq) ^ (rB1 & 7)) << 3)];
            acc[0][0] = __builtin_amdgcn_mfma_f32_16x16x32_bf16(a0, b0, acc[0][0], 0, 0, 0);
            acc[0][1] = __builtin_amdgcn_mfma_f32_16x16x32_bf16(a0, b1, acc[0][1], 0, 0, 0);
            acc[1][0] = __builtin_amdgcn_mfma_f32_16x16x32_bf16(a1, b0, acc[1][0], 0, 0, 0);
            acc[1][1] = __builtin_amdgcn_mfma_f32_16x16x32_bf16(a1, b1, acc[1][1], 0, 0, 0);
        }
        __syncthreads();
    }
    #pragma unroll
    for (int m = 0; m < 2; ++m) {
        #pragma unroll
        for (int n = 0; n < 2; ++n) {
            int col = cb + wc + n*16 + fr;
            if (col >= N) continue;
            float bv = bias[col];
            #pragma unroll
            for (int r = 0; r < 4; ++r) {
                int row = rb + wr + m*16 + fq*4 + r;
                if (row >= M) continue;
                float v = acc[m][n][r] + bv;
                if (act == 1) v = 0.5f * v * (1.f + erff(v * 0.70710678118654752f));
                if (qkvb) {
                    if (col < 512) {
                        if (col < 256) v *= QSCALE;
                        qkvb[(size_t)row*768 + col] = f2b(v);
                    } else {
                        int b = row / S, s = row - b*S;
                        int hd = col - 512;                 // h*32 + d
                        vTb[((size_t)(b*Hh + (hd >> 5))*DH + (hd & 31))*S + s] = f2b(v);
                    }
                } else if (Cb) {
                    Cb[(size_t)row*N + col] = f2b(v);
                } else {
                    Cf[(size_t)row*N + col] = v;
                }
            }
        }
    }
}

// ---- fused GEMM (N=256) + residual add + LayerNorm, in-place on xres ----
// One block per 64-row stripe; 4 waves, wave w owns cols [w*64, w*64+64).
// xres := LN(xres + A@W^T + bias) * lnw + lnb.  M%64==0, K%64==0.
__global__ __launch_bounds__(256) void
k_gemm_ln(const short* __restrict__ A, const short* __restrict__ W,
          const float* __restrict__ bias, short* __restrict__ xres,
          const float* __restrict__ lnw, const float* __restrict__ lnb,
          int M, int K)
{
    __shared__ short As[64][64];
    __shared__ short Ws[256][64];
    __shared__ float rsum[4][64];
    __shared__ float rsq[4][64];
    int tid = threadIdx.x;
    int lane = tid & 63, wave = tid >> 6;
    int rb = blockIdx.x * 64;
    int fr = lane & 15, fq = lane >> 4;
    f32x4 acc[4][4];
    #pragma unroll
    for (int mi = 0; mi < 4; ++mi)
        #pragma unroll
        for (int nj = 0; nj < 4; ++nj) acc[mi][nj] = (f32x4)0.f;
    int rl = lane >> 3, cl = lane & 7;
    for (int kk0 = 0; kk0 < K; kk0 += 64) {
        #pragma unroll
        for (int j = 0; j < 2; ++j) {
            int r = wave*16 + 8*j + rl;
            int cs = cl ^ (r & 7);
            gl_lds16(A + (size_t)(rb + r)*K + kk0 + cs*8, &As[wave*16 + 8*j][0]);
        }
        #pragma unroll
        for (int j = 0; j < 8; ++j) {
            int r = wave*64 + 8*j + rl;
            int cs = cl ^ (r & 7);
            gl_lds16(W + (size_t)r*K + kk0 + cs*8, &Ws[wave*64 + 8*j][0]);
        }
        __syncthreads();
        #pragma unroll
        for (int t = 0; t < 2; ++t) {
            bf16x8 av[4], bv[4];
            #pragma unroll
            for (int mi = 0; mi < 4; ++mi) {
                int rA = mi*16 + fr;
                av[mi] = *(const bf16x8*)&As[rA][(((4*t + fq) ^ (rA & 7)) << 3)];
            }
            #pragma unroll
            for (int nj = 0; nj < 4; ++nj) {
                int rB = wave*64 + nj*16 + fr;
                bv[nj] = *(const bf16x8*)&Ws[rB][(((4*t + fq) ^ (rB & 7)) << 3)];
            }
            #pragma unroll
            for (int mi = 0; mi < 4; ++mi)
                #pragma unroll
                for (int nj = 0; nj < 4; ++nj)
                    acc[mi][nj] = __builtin_amdgcn_mfma_f32_16x16x32_bf16(
                        av[mi], bv[nj], acc[mi][nj], 0, 0, 0);
        }
        __syncthreads();
    }
    // epilogue: residual add + per-row stats (partial per wave)
    float lw[4], lb[4], bs[4];
    #pragma unroll
    for (int nj = 0; nj < 4; ++nj) {
        int col = wave*64 + nj*16 + fr;
        bs[nj] = bias[col]; lw[nj] = lnw[col]; lb[nj] = lnb[col];
    }
    #pragma unroll
    for (int mi = 0; mi < 4; ++mi) {
        #pragma unroll
        for (int r = 0; r < 4; ++r) {
            int rowl = mi*16 + fq*4 + r;
            size_t rowg = (size_t)(rb + rowl);
            float s = 0.f, q = 0.f;
            #pragma unroll
            for (int nj = 0; nj < 4; ++nj) {
                int col = wave*64 + nj*16 + fr;
                float v = acc[mi][nj][r] + bs[nj] + b2f(xres[rowg*E + col]);
                acc[mi][nj][r] = v;
                s += v; q += v*v;
            }
            s += __shfl_xor(s, 1); q += __shfl_xor(q, 1);
            s += __shfl_xor(s, 2); q += __shfl_xor(q, 2);
            s += __shfl_xor(s, 4); q += __shfl_xor(q, 4);
            s += __shfl_xor(s, 8); q += __shfl_xor(q, 8);
            if (fr == 0) { rsum[wave][rowl] = s; rsq[wave][rowl] = q; }
        }
    }
    __syncthreads();
    #pragma unroll
    for (int mi = 0; mi < 4; ++mi) {
        #pragma unroll
        for (int r = 0; r < 4; ++r) {
            int rowl = mi*16 + fq*4 + r;
            size_t rowg = (size_t)(rb + rowl);
            float tot  = rsum[0][rowl] + rsum[1][rowl] + rsum[2][rowl] + rsum[3][rowl];
            float totq = rsq[0][rowl]  + rsq[1][rowl]  + rsq[2][rowl]  + rsq[3][rowl];
            float mean = tot * (1.f/E);
            float var  = fmaxf(totq * (1.f/E) - mean*mean, 0.f);
            float rstd = 1.f / sqrtf(var + 1e-5f);
            #pragma unroll
            for (int nj = 0; nj < 4; ++nj) {
                int col = wave*64 + nj*16 + fr;
                xres[rowg*E + col] = f2b((acc[mi][nj][r] - mean)*rstd*lw[nj] + lb[nj]);
            }
        }
    }
}

// ---- MFMA flash attention (round-17 form): dbuf K/V, branch-free tiles ----
// 128 thr = 2 waves (16 q each), KBLK=64, no-max exp2 softmax (scores bounded).
__global__ __launch_bounds__(128) void
k_fattn(const short* __restrict__ qkvb, const short* __restrict__ vTb,
        short* __restrict__ o, int S)
{
    __shared__ short Ks[2][64][40];
    __shared__ short Vt[2][32][72];
    int nqt = (S + 31) >> 5;
    int bi = blockIdx.x;
    int qt = bi % nqt, bh = bi / nqt;        // bh = b*Hh + h
    int h = bh & 7, b = bh >> 3;
    int q0 = qt << 5;
    int tid = threadIdx.x;
    int lane = tid & 63, wave = tid >> 6;
    int fr = lane & 15, fq = lane >> 4;
    bf16x8 qfrag = (bf16x8)0;
    int qg = q0 + wave*16 + fr;
    if (qg < S)
        qfrag = *(const bf16x8*)(qkvb + (size_t)(b*S+qg)*768 + h*DH + 8*fq);
    f32x4 acc0 = (f32x4)0.f, acc1 = (f32x4)0.f;   // O^T rows d=4fq+r (+16), col q
    float lpart = 0.f;
    int krow = tid >> 1, kh = (tid & 1) * 16;
    int vrow = tid >> 2, vk4 = (tid & 3) * 16;
    const short* kbase = qkvb + (size_t)(b*S)*768 + 256 + h*DH + (size_t)krow*768 + kh;
    const short* vTh = vTb + (size_t)bh*DH*S + (size_t)vrow*S + vk4;
    int src1 = fr + ((fq & 1) << 5);
    int src2 = src1 + 16;
    bool sel = (fq >> 1) != 0;
    int nt = (S + 63) >> 6;
    bool tail = (S & 63) != 0;
    bf16x8 kr0, kr1, vr0, vr1;      // in-flight staging regs (T14 split)
    auto LOADF = [&](int t) {       // full tile: no bounds checks
        const short* src = kbase + (size_t)(t << 6)*768;
        kr0 = *(const bf16x8*)src;
        kr1 = *(const bf16x8*)(src + 8);
        const short* vs = vTh + (t << 6);
        vr0 = *(const bf16x8*)vs;
        vr1 = *(const bf16x8*)(vs + 8);
    };
    auto LOADT = [&](int t) {       // tail tile (encoder only)
        int kg = (t << 6) + krow;
        if (kg < S) {
            const short* src = kbase + (size_t)(t << 6)*768;
            kr0 = *(const bf16x8*)src;
            kr1 = *(const bf16x8*)(src + 8);
        } else { kr0 = (bf16x8)0; kr1 = (bf16x8)0; }
        if ((t << 6) + vk4 < S) {   // 16-chunk all-or-nothing (S % 16 == 0)
            const short* vs = vTh + (t << 6);
            vr0 = *(const bf16x8*)vs;
            vr1 = *(const bf16x8*)(vs + 8);
        } else { vr0 = (bf16x8)0; vr1 = (bf16x8)0; }
    };
    auto WRITE = [&](int p) {
        *(bf16x8*)&Ks[p][krow][kh]      = kr0;
        *(bf16x8*)&Ks[p][krow][kh + 8]  = kr1;
        *(bf16x8*)&Vt[p][vrow][vk4]     = vr0;
        *(bf16x8*)&Vt[p][vrow][vk4 + 8] = vr1;
    };
    if (tail && nt == 1) LOADT(0); else LOADF(0);
    WRITE(0);
    __syncthreads();
    for (int t = 0; t < nt; ++t) {
        int p = t & 1;
        bool masked = tail && (t == nt - 1);
        if (t + 1 < nt) {
            if (tail && (t + 1 == nt - 1)) LOADT(t + 1); else LOADF(t + 1);
        }
        f32x4 st[4];
        #pragma unroll
        for (int kt = 0; kt < 4; ++kt) {
            bf16x8 kf = *(const bf16x8*)&Ks[p][kt*16 + fr][8*fq];
            st[kt] = __builtin_amdgcn_mfma_f32_16x16x32_bf16(kf, qfrag, (f32x4)0.f, 0, 0, 0);
        }
        if (masked) {
            int kt0 = t << 6;
            #pragma unroll
            for (int kt = 0; kt < 4; ++kt)
                #pragma unroll
                for (int r = 0; r < 4; ++r)
                    if (kt0 + kt*16 + 4*fq + r >= S) st[kt][r] = -1e30f;
        }
        float tsum = 0.f;
        unsigned pk[4][2];
        #pragma unroll
        for (int kt = 0; kt < 4; ++kt) {
            float p0 = exp2f(st[kt][0]), p1 = exp2f(st[kt][1]);
            float p2 = exp2f(st[kt][2]), p3 = exp2f(st[kt][3]);
            tsum += (p0 + p1) + (p2 + p3);
            pk[kt][0] = cvt_pk(p0, p1);
            pk[kt][1] = cvt_pk(p2, p3);
        }
        lpart += tsum;
        #pragma unroll
        for (int t2 = 0; t2 < 2; ++t2) {
            unsigned a0 = __shfl(pk[2*t2][0], src1),   a1 = __shfl(pk[2*t2][1], src1);
            unsigned a2 = __shfl(pk[2*t2][0], src2),   a3 = __shfl(pk[2*t2][1], src2);
            unsigned b0 = __shfl(pk[2*t2+1][0], src1), b1 = __shfl(pk[2*t2+1][1], src1);
            unsigned b2 = __shfl(pk[2*t2+1][0], src2), b3 = __shfl(pk[2*t2+1][1], src2);
            union { unsigned u[4]; bf16x8 v; } B2;
            B2.u[0] = sel ? b0 : a0;
            B2.u[1] = sel ? b1 : a1;
            B2.u[2] = sel ? b2 : a2;
            B2.u[3] = sel ? b3 : a3;
            bf16x8 v0 = *(const bf16x8*)&Vt[p][fr][t2*32 + 8*fq];
            bf16x8 v1 = *(const bf16x8*)&Vt[p][16 + fr][t2*32 + 8*fq];
            acc0 = __builtin_amdgcn_mfma_f32_16x16x32_bf16(v0, B2.v, acc0, 0, 0, 0);
            acc1 = __builtin_amdgcn_mfma_f32_16x16x32_bf16(v1, B2.v, acc1, 0, 0, 0);
        }
        if (t + 1 < nt) WRITE(p ^ 1);         // write next tile to other buffer
        __syncthreads();
    }
    float lsum = lpart;
    lsum += __shfl_xor(lsum, 16);
    lsum += __shfl_xor(lsum, 32);
    if (qg < S) {
        float inv = 1.f / lsum;
        short* op = o + (size_t)(b*S + qg)*E + h*DH;
        s16x4 o0 = { f2b(acc0[0]*inv), f2b(acc0[1]*inv), f2b(acc0[2]*inv), f2b(acc0[3]*inv) };
        s16x4 o1 = { f2b(acc1[0]*inv), f2b(acc1[1]*inv), f2b(acc1[2]*inv), f2b(acc1[3]*inv) };
        *(s16x4*)&op[4*fq]      = o0;
        *(s16x4*)&op[16 + 4*fq] = o1;
    }
}

__global__ void k_mean(const short* __restrict__ xv, float* __restrict__ mb)
{
    int b = blockIdx.x, tid = threadIdx.x;
    float s = 0.f;
    for (int r = 0; r < NKEEP; ++r) s += b2f(xv[((size_t)b*NKEEP + r)*E + tid]);
    mb[b*E + tid] = s * (1.f/NKEEP);
}

__global__ void k_cls(const float* __restrict__ mb, const float* __restrict__ cw,
                      const float* __restrict__ cb, float* __restrict__ out)
{
    int t = threadIdx.x;
    if (t < Bb*NC) {
        int b = t / NC, c = t % NC;
        float acc = cb[c];
        for (int k = 0; k < E; ++k) acc += mb[b*E+k]*cw[c*E+k];
        out[t] = acc;
    }
}

// ---- scatter: xdb[b*NP+n] = (keep? enc : mask_token) + dec_pos (bf16) ----
__global__ void k_scatter(const short* __restrict__ visb, const int* __restrict__ keep_pos,
                          const float* __restrict__ mtok, const float* __restrict__ dpos,
                          short* __restrict__ xdb)
{
    int bn = blockIdx.x; int b = bn / NP, n = bn % NP;
    int t = threadIdx.x;
    int s = keep_pos[bn];
    float base = (s >= 0) ? b2f(visb[((size_t)b*NKEEP + s)*E + t]) : mtok[t];
    xdb[(size_t)bn*E + t] = f2b(base + dpos[(size_t)n*E + t]);
}

extern "C" void kernel_launch(void* const* d_in, const int* in_sizes, int n_in,
                              void* d_out, int out_size, void* d_ws, size_t ws_size,
                              hipStream_t stream)
{
    // d_in in setup_inputs() DICT order.
    const float* x        = (const float*)d_in[0];
    const float* noise    = (const float*)d_in[1];
    const float* patch_w  = (const float*)d_in[2];
    const float* patch_b  = (const float*)d_in[3];
    const float* pos      = (const float*)d_in[4];
    const float* dpos     = (const float*)d_in[5];
    const float* mtok     = (const float*)d_in[6];
    const float* pred_w   = (const float*)d_in[7];
    const float* pred_b   = (const float*)d_in[8];
    const float* cls_w    = (const float*)d_in[9];
    const float* cls_b    = (const float*)d_in[10];
    const float* enc_w[12]; for (int i = 0; i < 12; ++i) enc_w[i] = (const float*)d_in[11+i];
    const float* dec_w[12]; for (int i = 0; i < 12; ++i) dec_w[i] = (const float*)d_in[23+i];

    float* out = (float*)d_out;
    float* out_pred = out;                 // 864000
    float* out_xg   = out + 864000;        // 864000
    float* out_mask = out + 1728000;       // 6912
    float* out_cls  = out + 1734912;       // 160

    // Workspace (~49.4 MB), all-bf16 activations + bf16 weight arena.
    short* S0   = (short*)d_ws;
    short* qkvb = S0;                      // 6912*768  = 5308416
    short* bigb = qkvb + 5308416;          // 6912*1024 = 7077888 (ffn hidden)
    short* vTb  = bigb + 7077888;          // 4*8*32*1728 = 1769472
    short* visb = vTb  + 1769472;          // 1728*256  = 442368
    short* xdb  = visb + 442368;           // 6912*256  = 1769472
    short* c1b  = xdb  + 1769472;          // 1769472
    short* c2b  = c1b  + 1769472;          // 1769472 (unused now)
    short* wb   = c2b  + 1769472;          // 4751360 bf16 weight arena (pred padded)
    float* mb   = (float*)(wb + 4751360);  // 1024
    int* shuf   = (int*)(mb + 1024);       // 6912
    int* keep   = shuf + Bb*NP;            // 6912

    // ---- weight arena layout: per layer {qkv, out, ffn1, ffn2} ----
    const int LSTRIDE = 786432;            // 196608+65536+262144+262144
    W2BTab tab;
    int wi = 0;
    size_t off = 0;
    auto addw = [&](const float* src, int n, int npad) {
        tab.e[wi].src = src; tab.e[wi].dst = wb + off;
        tab.e[wi].n = n; tab.e[wi].npad = npad;
        ++wi; off += npad;
    };
    for (int l = 0; l < LE; ++l) {
        addw(enc_w[0] + (size_t)l*3*E*E, 3*E*E, 3*E*E);
        addw(enc_w[2] + (size_t)l*E*E,   E*E,   E*E);
        addw(enc_w[8] + (size_t)l*4*E*E, 4*E*E, 4*E*E);
        addw(enc_w[10]+ (size_t)l*4*E*E, 4*E*E, 4*E*E);
    }
    for (int l = 0; l < LD; ++l) {
        addw(dec_w[0] + (size_t)l*3*E*E, 3*E*E, 3*E*E);
        addw(dec_w[2] + (size_t)l*E*E,   E*E,   E*E);
        addw(dec_w[8] + (size_t)l*4*E*E, 4*E*E, 4*E*E);
        addw(dec_w[10]+ (size_t)l*4*E*E, 4*E*E, 4*E*E);
    }
    addw(pred_w, PP3*E, 128*E);            // pad to 128 rows (N=125 GEMM staging)
    hipLaunchKernelGGL(k_w2b, dim3(128, 25), dim3(256), 0, stream, tab);

    auto gemm = [&](const short* A, const short* W, const float* bias,
                    float* Cf, short* Cb, int M, int N, int K, int act,
                    short* qb, short* vb, int Sv) {
        dim3 g((N+63)/64, (M+63)/64);
        hipLaunchKernelGGL(k_mgemm, g, dim3(256), 0, stream, A, W, bias,
                           Cf, Cb, M, N, K, act, qb, vb, Sv);
    };

    // xbuf = bf16 activations [Bl*S][E]; wbase = this stack's weight arena base
    auto layer = [&](short* xbuf, int Bl, int S, const float* const* Wp,
                     const short* wbase, int l) {
        int M = Bl * S;
        int nqt = (S + 31) / 32;
        const short* wq = wbase + (size_t)l*LSTRIDE;
        const short* wo = wq + 3*E*E;
        const short* w1 = wo + E*E;
        const short* w2 = w1 + 4*E*E;
        gemm(xbuf, wq, Wp[1] + l*3*E, nullptr, nullptr, M, 3*E, E, 0, qkvb, vTb, S);
        k_fattn<<<Bl*Hh*nqt, 128, 0, stream>>>(qkvb, vTb, c1b, S);
        k_gemm_ln<<<M/64, 256, 0, stream>>>(c1b, wo, Wp[3] + l*E, xbuf,
                                            Wp[4] + l*E, Wp[5] + l*E, M, E);
        gemm(xbuf, w1, Wp[9] + l*4*E, nullptr, bigb, M, 4*E, E, 1, nullptr, nullptr, 1);
        k_gemm_ln<<<M/64, 256, 0, stream>>>(bigb, w2, Wp[11] + l*E, xbuf,
                                            Wp[6] + l*E, Wp[7] + l*E, M, 4*E);
    };

    k_rank<<<Bb*7, 256, 0, stream>>>(noise, shuf, keep, out_mask);
    k_xg<<<Bb*NP, 128, 0, stream>>>(x, out_xg);
    k_patch_vis<<<Bb*NKEEP, 256, 0, stream>>>(x, patch_w, patch_b, pos, shuf, visb);

    const short* enc_wb = wb;
    const short* dec_wb = wb + (size_t)LE*LSTRIDE;
    const short* pred_wb = wb + (size_t)(LE+LD)*LSTRIDE;

    for (int l = 0; l < LE; ++l) layer(visb, Bb, NKEEP, enc_w, enc_wb, l);

    k_mean<<<Bb, 256, 0, stream>>>(visb, mb);
    k_cls<<<1, 256, 0, stream>>>(mb, cls_w, cls_b, out_cls);

    k_scatter<<<Bb*NP, 256, 0, stream>>>(visb, keep, mtok, dpos, xdb);
    for (int l = 0; l < LD; ++l) layer(xdb, Bb, NP, dec_w, dec_wb, l);
    gemm(xdb, pred_wb, pred_b, out_pred, nullptr, Bb*NP, PP3, E, 0, nullptr, nullptr, 1);
}

// Round 20
// 558.139 us; speedup vs baseline: 1.1770x; 1.1770x over previous
//
#include <hip/hip_runtime.h>
#include <hip/hip_bf16.h>
#include <math.h>

#define E 256
#define Hh 8
#define DH 32
#define NP 1728
#define PP3 125
#define Bb 4
#define NUM_MASKC 1296
#define NKEEP 432
#define LE 4
#define LD 2
#define NC 40

typedef __attribute__((ext_vector_type(4))) float f32x4;
typedef __attribute__((ext_vector_type(8))) short bf16x8;
typedef __attribute__((ext_vector_type(4))) short s16x4;

#define QSCALE 0.25505654708402214f   /* (1/sqrt(32)) * log2(e) */

__device__ inline short f2b(float f) {
    __hip_bfloat16 h = __float2bfloat16(f);   // HW RNE cvt
    return *reinterpret_cast<short*>(&h);
}
__device__ inline float b2f(short s) {
    union { unsigned u; float f; } v; v.u = ((unsigned)(unsigned short)s) << 16;
    return v.f;
}
__device__ inline unsigned cvt_pk(float lo, float hi) {
    unsigned r;
    asm("v_cvt_pk_bf16_f32 %0, %1, %2" : "=v"(r) : "v"(lo), "v"(hi));
    return r;
}

// ---- one-shot fp32 -> bf16 weight conversion (25 matrices, zero-padded) ----
struct W2B { const float* src; short* dst; int n; int npad; };
struct W2BTab { W2B e[25]; };
__global__ void k_w2b(W2BTab tab) {
    W2B w = tab.e[blockIdx.y];
    int i = (blockIdx.x*256 + threadIdx.x) * 8;
    if (i + 8 <= w.n) {
        float4 a = *(const float4*)(w.src + i);
        float4 b = *(const float4*)(w.src + i + 4);
        short t[8] = {f2b(a.x),f2b(a.y),f2b(a.z),f2b(a.w),
                      f2b(b.x),f2b(b.y),f2b(b.z),f2b(b.w)};
        *(bf16x8*)(w.dst + i) = *(const bf16x8*)t;
    } else if (i < w.npad) {
        *(bf16x8*)(w.dst + i) = (bf16x8)0;
    }
}

// ---- stable rank == jnp.argsort: 7 blocks per batch row, noise in LDS ----
__global__ void k_rank(const float* __restrict__ noise, int* __restrict__ shuf,
                       int* __restrict__ keep_pos, float* __restrict__ out_mask)
{
    __shared__ float ns[NP];
    int b = blockIdx.x / 7, it = blockIdx.x % 7;
    const float* nr = noise + (size_t)b*NP;
    int tid = threadIdx.x;
    for (int j = tid; j < NP; j += 256) ns[j] = nr[j];
    __syncthreads();
    int i = it*256 + tid;
    if (i < NP) {
        float ni = ns[i];
        int rank = 0;
        for (int j = 0; j < NP; ++j) {
            float nj = ns[j];
            rank += (nj < ni) || (nj == ni && j < i);
        }
        shuf[b*NP + rank] = i;
        keep_pos[b*NP + i] = (rank >= NUM_MASKC) ? (rank - NUM_MASKC) : -1;
        out_mask[b*NP + i] = (rank < NUM_MASKC) ? 1.0f : 0.0f;
    }
}

// ---- xg output only ----
__global__ void k_xg(const float* __restrict__ x, float* __restrict__ out_xg)
{
    int bn = blockIdx.x;            // b*NP + n
    int b = bn / NP, n = bn % NP;
    int a0 = n / 144, r = n % 144, b0 = r / 12, c0 = r % 12;
    int t = threadIdx.x;
    if (t < PP3) {
        int pa = t / 25, rem = t % 25, pbq = rem / 5, pc = rem % 5;
        out_xg[(size_t)bn*PP3 + t] =
            x[(size_t)b*216000 + (size_t)(a0*5+pa)*3600 + (b0*5+pbq)*60 + (c0*5+pc)];
    }
}

// ---- patch extract + embed for VISIBLE tokens only (bf16 out) ----
__global__ void k_patch_vis(const float* __restrict__ x, const float* __restrict__ pw,
                            const float* __restrict__ pb, const float* __restrict__ pos,
                            const int* __restrict__ shuf, short* __restrict__ visb)
{
    int row = blockIdx.x;            // b*NKEEP + s
    int b = row / NKEEP, s = row % NKEEP;
    int n = shuf[b*NP + NUM_MASKC + s];
    int a0 = n / 144, r = n % 144, b0 = r / 12, c0 = r % 12;
    __shared__ float patch[PP3];
    int t = threadIdx.x;
    if (t < PP3) {
        int pa = t / 25, rem = t % 25, pbq = rem / 5, pc = rem % 5;
        patch[t] = x[(size_t)b*216000 + (size_t)(a0*5+pa)*3600 + (b0*5+pbq)*60 + (c0*5+pc)];
    }
    __syncthreads();
    float acc = pb[t] + pos[(size_t)n*E + t];
    const float* w = pw + (size_t)t*PP3;
    for (int k = 0; k < PP3; ++k) acc += patch[k] * w[k];
    visb[(size_t)row*E + t] = f2b(acc);
}

// ---- bf16 MFMA GEMM 64x64, reg-staged double-buffer (T14) + XOR swizzle ----
// Loads for chunk t+1 issue BEFORE compute(t); ds_write after; one barrier/chunk
// that drains only LDS writes (no in-flight global loads killed).
// out modes: qkvb!=null -> qkv split ; else Cb!=null -> bf16 C ; else fp32 Cf.
__global__ __launch_bounds__(256) void
k_mgemm(const short* __restrict__ A, const short* __restrict__ W,
        const float* __restrict__ bias, float* __restrict__ Cf,
        short* __restrict__ Cb, int M, int N, int K, int act,
        short* __restrict__ qkvb, short* __restrict__ vTb, int S)
{
    __shared__ short As[2][64][64];   // 16B chunk c of row r holds global chunk c^(r&7)
    __shared__ short Ws[2][64][64];
    int tid = threadIdx.x;
    int lane = tid & 63, wave = tid >> 6;
    int rb = blockIdx.y * 64, cb = blockIdx.x * 64;
    int wr = (wave >> 1) * 32, wc = (wave & 1) * 32;
    int fr = lane & 15, fq = lane >> 4;
    f32x4 acc[2][2];
    #pragma unroll
    for (int m = 0; m < 2; ++m)
        #pragma unroll
        for (int n = 0; n < 2; ++n) acc[m][n] = (f32x4)0.f;
    int sr = tid >> 2;                 // staging row 0..63
    int sc0 = (tid & 3) * 2;           // first of two 8-short chunks
    const short* Arow = A + (size_t)(rb + sr)*K + sc0*8;
    const short* Wrow = W + (size_t)(cb + sr)*K + sc0*8;
    int c0x = (sc0     ^ (sr & 7)) * 8;
    int c1x = ((sc0+1) ^ (sr & 7)) * 8;
    bf16x8 ra0, ra1, rw0, rw1;
    auto LOADR = [&](int t) {
        const short* a = Arow + (t << 6);
        ra0 = *(const bf16x8*)a;
        ra1 = *(const bf16x8*)(a + 8);
        const short* w = Wrow + (t << 6);
        rw0 = *(const bf16x8*)w;
        rw1 = *(const bf16x8*)(w + 8);
    };
    auto WRITE = [&](int p) {
        *(bf16x8*)&As[p][sr][c0x] = ra0;
        *(bf16x8*)&As[p][sr][c1x] = ra1;
        *(bf16x8*)&Ws[p][sr][c0x] = rw0;
        *(bf16x8*)&Ws[p][sr][c1x] = rw1;
    };
    int nk = K >> 6;
    LOADR(0); WRITE(0);
    __syncthreads();
    for (int t = 0; t < nk; ++t) {
        int p = t & 1;
        if (t + 1 < nk) LOADR(t + 1);      // global latency hides under MFMA below
        #pragma unroll
        for (int tt = 0; tt < 2; ++tt) {
            int rA0 = wr + fr, rA1 = wr + 16 + fr;
            int rB0 = wc + fr, rB1 = wc + 16 + fr;
            bf16x8 a0 = *(const bf16x8*)&As[p][rA0][(((4*tt + fq) ^ (rA0 & 7)) << 3)];
            bf16x8 a1 = *(const bf16x8*)&As[p][rA1][(((4*tt + fq) ^ (rA1 & 7)) << 3)];
            bf16x8 b0 = *(const bf16x8*)&Ws[p][rB0][(((4*tt + fq) ^ (rB0 & 7)) << 3)];
            bf16x8 b1 = *(const bf16x8*)&Ws[p][rB1][(((4*tt + fq) ^ (rB1 & 7)) << 3)];
            acc[0][0] = __builtin_amdgcn_mfma_f32_16x16x32_bf16(a0, b0, acc[0][0], 0, 0, 0);
            acc[0][1] = __builtin_amdgcn_mfma_f32_16x16x32_bf16(a0, b1, acc[0][1], 0, 0, 0);
            acc[1][0] = __builtin_amdgcn_mfma_f32_16x16x32_bf16(a1, b0, acc[1][0], 0, 0, 0);
            acc[1][1] = __builtin_amdgcn_mfma_f32_16x16x32_bf16(a1, b1, acc[1][1], 0, 0, 0);
        }
        if (t + 1 < nk) WRITE(p ^ 1);      // vmcnt wait folded here by data dep
        __syncthreads();
    }
    #pragma unroll
    for (int m = 0; m < 2; ++m) {
        #pragma unroll
        for (int n = 0; n < 2; ++n) {
            int col = cb + wc + n*16 + fr;
            if (col >= N) continue;
            float bv = bias[col];
            #pragma unroll
            for (int r = 0; r < 4; ++r) {
                int row = rb + wr + m*16 + fq*4 + r;
                if (row >= M) continue;
                float v = acc[m][n][r] + bv;
                if (act == 1) v = 0.5f * v * (1.f + erff(v * 0.70710678118654752f));
                if (qkvb) {
                    if (col < 512) {
                        if (col < 256) v *= QSCALE;
                        qkvb[(size_t)row*768 + col] = f2b(v);
                    } else {
                        int b = row / S, s = row - b*S;
                        int hd = col - 512;                 // h*32 + d
                        vTb[((size_t)(b*Hh + (hd >> 5))*DH + (hd & 31))*S + s] = f2b(v);
                    }
                } else if (Cb) {
                    Cb[(size_t)row*N + col] = f2b(v);
                } else {
                    Cf[(size_t)row*N + col] = v;
                }
            }
        }
    }
}

// ---- MFMA flash attention (round-17 form): dbuf K/V, branch-free tiles ----
// 128 thr = 2 waves (16 q each), KBLK=64, no-max exp2 softmax (scores bounded).
__global__ __launch_bounds__(128) void
k_fattn(const short* __restrict__ qkvb, const short* __restrict__ vTb,
        short* __restrict__ o, int S)
{
    __shared__ short Ks[2][64][40];
    __shared__ short Vt[2][32][72];
    int nqt = (S + 31) >> 5;
    int bi = blockIdx.x;
    int qt = bi % nqt, bh = bi / nqt;        // bh = b*Hh + h
    int h = bh & 7, b = bh >> 3;
    int q0 = qt << 5;
    int tid = threadIdx.x;
    int lane = tid & 63, wave = tid >> 6;
    int fr = lane & 15, fq = lane >> 4;
    bf16x8 qfrag = (bf16x8)0;
    int qg = q0 + wave*16 + fr;
    if (qg < S)
        qfrag = *(const bf16x8*)(qkvb + (size_t)(b*S+qg)*768 + h*DH + 8*fq);
    f32x4 acc0 = (f32x4)0.f, acc1 = (f32x4)0.f;   // O^T rows d=4fq+r (+16), col q
    float lpart = 0.f;
    int krow = tid >> 1, kh = (tid & 1) * 16;
    int vrow = tid >> 2, vk4 = (tid & 3) * 16;
    const short* kbase = qkvb + (size_t)(b*S)*768 + 256 + h*DH + (size_t)krow*768 + kh;
    const short* vTh = vTb + (size_t)bh*DH*S + (size_t)vrow*S + vk4;
    int src1 = fr + ((fq & 1) << 5);
    int src2 = src1 + 16;
    bool sel = (fq >> 1) != 0;
    int nt = (S + 63) >> 6;
    bool tail = (S & 63) != 0;
    bf16x8 kr0, kr1, vr0, vr1;      // in-flight staging regs (T14 split)
    auto LOADF = [&](int t) {       // full tile: no bounds checks
        const short* src = kbase + (size_t)(t << 6)*768;
        kr0 = *(const bf16x8*)src;
        kr1 = *(const bf16x8*)(src + 8);
        const short* vs = vTh + (t << 6);
        vr0 = *(const bf16x8*)vs;
        vr1 = *(const bf16x8*)(vs + 8);
    };
    auto LOADT = [&](int t) {       // tail tile (encoder only)
        int kg = (t << 6) + krow;
        if (kg < S) {
            const short* src = kbase + (size_t)(t << 6)*768;
            kr0 = *(const bf16x8*)src;
            kr1 = *(const bf16x8*)(src + 8);
        } else { kr0 = (bf16x8)0; kr1 = (bf16x8)0; }
        if ((t << 6) + vk4 < S) {   // 16-chunk all-or-nothing (S % 16 == 0)
            const short* vs = vTh + (t << 6);
            vr0 = *(const bf16x8*)vs;
            vr1 = *(const bf16x8*)(vs + 8);
        } else { vr0 = (bf16x8)0; vr1 = (bf16x8)0; }
    };
    auto WRITE = [&](int p) {
        *(bf16x8*)&Ks[p][krow][kh]      = kr0;
        *(bf16x8*)&Ks[p][krow][kh + 8]  = kr1;
        *(bf16x8*)&Vt[p][vrow][vk4]     = vr0;
        *(bf16x8*)&Vt[p][vrow][vk4 + 8] = vr1;
    };
    if (tail && nt == 1) LOADT(0); else LOADF(0);
    WRITE(0);
    __syncthreads();
    for (int t = 0; t < nt; ++t) {
        int p = t & 1;
        bool masked = tail && (t == nt - 1);
        if (t + 1 < nt) {
            if (tail && (t + 1 == nt - 1)) LOADT(t + 1); else LOADF(t + 1);
        }
        f32x4 st[4];
        #pragma unroll
        for (int kt = 0; kt < 4; ++kt) {
            bf16x8 kf = *(const bf16x8*)&Ks[p][kt*16 + fr][8*fq];
            st[kt] = __builtin_amdgcn_mfma_f32_16x16x32_bf16(kf, qfrag, (f32x4)0.f, 0, 0, 0);
        }
        if (masked) {
            int kt0 = t << 6;
            #pragma unroll
            for (int kt = 0; kt < 4; ++kt)
                #pragma unroll
                for (int r = 0; r < 4; ++r)
                    if (kt0 + kt*16 + 4*fq + r >= S) st[kt][r] = -1e30f;
        }
        float tsum = 0.f;
        unsigned pk[4][2];
        #pragma unroll
        for (int kt = 0; kt < 4; ++kt) {
            float p0 = exp2f(st[kt][0]), p1 = exp2f(st[kt][1]);
            float p2 = exp2f(st[kt][2]), p3 = exp2f(st[kt][3]);
            tsum += (p0 + p1) + (p2 + p3);
            pk[kt][0] = cvt_pk(p0, p1);
            pk[kt][1] = cvt_pk(p2, p3);
        }
        lpart += tsum;
        #pragma unroll
        for (int t2 = 0; t2 < 2; ++t2) {
            unsigned a0 = __shfl(pk[2*t2][0], src1),   a1 = __shfl(pk[2*t2][1], src1);
            unsigned a2 = __shfl(pk[2*t2][0], src2),   a3 = __shfl(pk[2*t2][1], src2);
            unsigned b0 = __shfl(pk[2*t2+1][0], src1), b1 = __shfl(pk[2*t2+1][1], src1);
            unsigned b2 = __shfl(pk[2*t2+1][0], src2), b3 = __shfl(pk[2*t2+1][1], src2);
            union { unsigned u[4]; bf16x8 v; } B2;
            B2.u[0] = sel ? b0 : a0;
            B2.u[1] = sel ? b1 : a1;
            B2.u[2] = sel ? b2 : a2;
            B2.u[3] = sel ? b3 : a3;
            bf16x8 v0 = *(const bf16x8*)&Vt[p][fr][t2*32 + 8*fq];
            bf16x8 v1 = *(const bf16x8*)&Vt[p][16 + fr][t2*32 + 8*fq];
            acc0 = __builtin_amdgcn_mfma_f32_16x16x32_bf16(v0, B2.v, acc0, 0, 0, 0);
            acc1 = __builtin_amdgcn_mfma_f32_16x16x32_bf16(v1, B2.v, acc1, 0, 0, 0);
        }
        if (t + 1 < nt) WRITE(p ^ 1);         // write next tile to other buffer
        __syncthreads();
    }
    float lsum = lpart;
    lsum += __shfl_xor(lsum, 16);
    lsum += __shfl_xor(lsum, 32);
    if (qg < S) {
        float inv = 1.f / lsum;
        short* op = o + (size_t)(b*S + qg)*E + h*DH;
        s16x4 o0 = { f2b(acc0[0]*inv), f2b(acc0[1]*inv), f2b(acc0[2]*inv), f2b(acc0[3]*inv) };
        s16x4 o1 = { f2b(acc1[0]*inv), f2b(acc1[1]*inv), f2b(acc1[2]*inv), f2b(acc1[3]*inv) };
        *(s16x4*)&op[4*fq]      = o0;
        *(s16x4*)&op[16 + 4*fq] = o1;
    }
}

// ---- x = LN(x + rsd) * w + b : wave per row, bf16 I/O, no barriers ----
__global__ __launch_bounds__(256) void
k_lnadd(short* __restrict__ x, const short* __restrict__ rsd,
        const float* __restrict__ w, const float* __restrict__ bv)
{
    int row = blockIdx.x*4 + (threadIdx.x >> 6);
    int lane = threadIdx.x & 63;
    int c0 = lane * 4;
    size_t base = (size_t)row*E + c0;
    s16x4 xv = *(const s16x4*)&x[base];
    s16x4 rv = *(const s16x4*)&rsd[base];
    float v[4];
    float s = 0.f, sq = 0.f;
    #pragma unroll
    for (int j = 0; j < 4; ++j) {
        v[j] = b2f(xv[j]) + b2f(rv[j]);
        s += v[j]; sq += v[j]*v[j];
    }
    #pragma unroll
    for (int off = 1; off < 64; off <<= 1) {
        s  += __shfl_xor(s, off);
        sq += __shfl_xor(sq, off);
    }
    float mean = s * (1.f/E);
    float var = fmaxf(sq * (1.f/E) - mean*mean, 0.f);
    float rstd = 1.f / sqrtf(var + 1e-5f);
    float4 wv = *(const float4*)&w[c0];
    float4 bb = *(const float4*)&bv[c0];
    s16x4 o;
    o[0] = f2b((v[0]-mean)*rstd*wv.x + bb.x);
    o[1] = f2b((v[1]-mean)*rstd*wv.y + bb.y);
    o[2] = f2b((v[2]-mean)*rstd*wv.z + bb.z);
    o[3] = f2b((v[3]-mean)*rstd*wv.w + bb.w);
    *(s16x4*)&x[base] = o;
}

__global__ void k_mean(const short* __restrict__ xv, float* __restrict__ mb)
{
    int b = blockIdx.x, tid = threadIdx.x;
    float s = 0.f;
    for (int r = 0; r < NKEEP; ++r) s += b2f(xv[((size_t)b*NKEEP + r)*E + tid]);
    mb[b*E + tid] = s * (1.f/NKEEP);
}

__global__ void k_cls(const float* __restrict__ mb, const float* __restrict__ cw,
                      const float* __restrict__ cb, float* __restrict__ out)
{
    int t = threadIdx.x;
    if (t < Bb*NC) {
        int b = t / NC, c = t % NC;
        float acc = cb[c];
        for (int k = 0; k < E; ++k) acc += mb[b*E+k]*cw[c*E+k];
        out[t] = acc;
    }
}

// ---- scatter: xdb[b*NP+n] = (keep? enc : mask_token) + dec_pos (bf16) ----
__global__ void k_scatter(const short* __restrict__ visb, const int* __restrict__ keep_pos,
                          const float* __restrict__ mtok, const float* __restrict__ dpos,
                          short* __restrict__ xdb)
{
    int bn = blockIdx.x; int b = bn / NP, n = bn % NP;
    int t = threadIdx.x;
    int s = keep_pos[bn];
    float base = (s >= 0) ? b2f(visb[((size_t)b*NKEEP + s)*E + t]) : mtok[t];
    xdb[(size_t)bn*E + t] = f2b(base + dpos[(size_t)n*E + t]);
}

extern "C" void kernel_launch(void* const* d_in, const int* in_sizes, int n_in,
                              void* d_out, int out_size, void* d_ws, size_t ws_size,
                              hipStream_t stream)
{
    // d_in in setup_inputs() DICT order.
    const float* x        = (const float*)d_in[0];
    const float* noise    = (const float*)d_in[1];
    const float* patch_w  = (const float*)d_in[2];
    const float* patch_b  = (const float*)d_in[3];
    const float* pos      = (const float*)d_in[4];
    const float* dpos     = (const float*)d_in[5];
    const float* mtok     = (const float*)d_in[6];
    const float* pred_w   = (const float*)d_in[7];
    const float* pred_b   = (const float*)d_in[8];
    const float* cls_w    = (const float*)d_in[9];
    const float* cls_b    = (const float*)d_in[10];
    const float* enc_w[12]; for (int i = 0; i < 12; ++i) enc_w[i] = (const float*)d_in[11+i];
    const float* dec_w[12]; for (int i = 0; i < 12; ++i) dec_w[i] = (const float*)d_in[23+i];

    float* out = (float*)d_out;
    float* out_pred = out;                 // 864000
    float* out_xg   = out + 864000;        // 864000
    float* out_mask = out + 1728000;       // 6912
    float* out_cls  = out + 1734912;       // 160

    // Workspace (~49.4 MB), all-bf16 activations + bf16 weight arena.
    short* S0   = (short*)d_ws;
    short* qkvb = S0;                      // 6912*768  = 5308416
    short* bigb = qkvb + 5308416;          // 6912*1024 = 7077888 (ffn hidden)
    short* vTb  = bigb + 7077888;          // 4*8*32*1728 = 1769472
    short* visb = vTb  + 1769472;          // 1728*256  = 442368
    short* xdb  = visb + 442368;           // 6912*256  = 1769472
    short* c1b  = xdb  + 1769472;          // 1769472
    short* c2b  = c1b  + 1769472;          // 1769472
    short* wb   = c2b  + 1769472;          // 4751360 bf16 weight arena (pred padded)
    float* mb   = (float*)(wb + 4751360);  // 1024
    int* shuf   = (int*)(mb + 1024);       // 6912
    int* keep   = shuf + Bb*NP;            // 6912

    // ---- weight arena layout: per layer {qkv, out, ffn1, ffn2} ----
    const int LSTRIDE = 786432;            // 196608+65536+262144+262144
    W2BTab tab;
    int wi = 0;
    size_t off = 0;
    auto addw = [&](const float* src, int n, int npad) {
        tab.e[wi].src = src; tab.e[wi].dst = wb + off;
        tab.e[wi].n = n; tab.e[wi].npad = npad;
        ++wi; off += npad;
    };
    for (int l = 0; l < LE; ++l) {
        addw(enc_w[0] + (size_t)l*3*E*E, 3*E*E, 3*E*E);
        addw(enc_w[2] + (size_t)l*E*E,   E*E,   E*E);
        addw(enc_w[8] + (size_t)l*4*E*E, 4*E*E, 4*E*E);
        addw(enc_w[10]+ (size_t)l*4*E*E, 4*E*E, 4*E*E);
    }
    for (int l = 0; l < LD; ++l) {
        addw(dec_w[0] + (size_t)l*3*E*E, 3*E*E, 3*E*E);
        addw(dec_w[2] + (size_t)l*E*E,   E*E,   E*E);
        addw(dec_w[8] + (size_t)l*4*E*E, 4*E*E, 4*E*E);
        addw(dec_w[10]+ (size_t)l*4*E*E, 4*E*E, 4*E*E);
    }
    addw(pred_w, PP3*E, 128*E);            // pad to 128 rows (N=125 GEMM staging)
    hipLaunchKernelGGL(k_w2b, dim3(128, 25), dim3(256), 0, stream, tab);

    auto gemm = [&](const short* A, const short* W, const float* bias,
                    float* Cf, short* Cb, int M, int N, int K, int act,
                    short* qb, short* vb, int Sv) {
        dim3 g((N+63)/64, (M+63)/64);
        hipLaunchKernelGGL(k_mgemm, g, dim3(256), 0, stream, A, W, bias,
                           Cf, Cb, M, N, K, act, qb, vb, Sv);
    };

    // xbuf = bf16 activations [Bl*S][E]; wbase = this stack's weight arena base
    auto layer = [&](short* xbuf, int Bl, int S, const float* const* Wp,
                     const short* wbase, int l) {
        int M = Bl * S;
        int nqt = (S + 31) / 32;
        const short* wq = wbase + (size_t)l*LSTRIDE;
        const short* wo = wq + 3*E*E;
        const short* w1 = wo + E*E;
        const short* w2 = w1 + 4*E*E;
        gemm(xbuf, wq, Wp[1] + l*3*E, nullptr, nullptr, M, 3*E, E, 0, qkvb, vTb, S);
        k_fattn<<<Bl*Hh*nqt, 128, 0, stream>>>(qkvb, vTb, c1b, S);
        gemm(c1b, wo, Wp[3] + l*E, nullptr, c2b, M, E, E, 0, nullptr, nullptr, 1);
        k_lnadd<<<M/4, 256, 0, stream>>>(xbuf, c2b, Wp[4] + l*E, Wp[5] + l*E);
        gemm(xbuf, w1, Wp[9] + l*4*E, nullptr, bigb, M, 4*E, E, 1, nullptr, nullptr, 1);
        gemm(bigb, w2, Wp[11] + l*E, nullptr, c2b, M, E, 4*E, 0, nullptr, nullptr, 1);
        k_lnadd<<<M/4, 256, 0, stream>>>(xbuf, c2b, Wp[6] + l*E, Wp[7] + l*E);
    };

    k_rank<<<Bb*7, 256, 0, stream>>>(noise, shuf, keep, out_mask);
    k_xg<<<Bb*NP, 128, 0, stream>>>(x, out_xg);
    k_patch_vis<<<Bb*NKEEP, 256, 0, stream>>>(x, patch_w, patch_b, pos, shuf, visb);

    const short* enc_wb = wb;
    const short* dec_wb = wb + (size_t)LE*LSTRIDE;
    const short* pred_wb = wb + (size_t)(LE+LD)*LSTRIDE;

    for (int l = 0; l < LE; ++l) layer(visb, Bb, NKEEP, enc_w, enc_wb, l);

    k_mean<<<Bb, 256, 0, stream>>>(visb, mb);
    k_cls<<<1, 256, 0, stream>>>(mb, cls_w, cls_b, out_cls);

    k_scatter<<<Bb*NP, 256, 0, stream>>>(visb, keep, mtok, dpos, xdb);
    for (int l = 0; l < LD; ++l) layer(xdb, Bb, NP, dec_w, dec_wb, l);
    gemm(xdb, pred_wb, pred_b, out_pred, nullptr, Bb*NP, PP3, E, 0, nullptr, nullptr, 1);
}

// Round 21
// 532.617 us; speedup vs baseline: 1.2334x; 1.0479x over previous
//
#include <hip/hip_runtime.h>
#include <hip/hip_bf16.h>
#include <math.h>

#define E 256
#define Hh 8
#define DH 32
#define NP 1728
#define PP3 125
#define Bb 4
#define NUM_MASKC 1296
#define NKEEP 432
#define LE 4
#define LD 2
#define NC 40

typedef __attribute__((ext_vector_type(4))) float f32x4;
typedef __attribute__((ext_vector_type(8))) short bf16x8;
typedef __attribute__((ext_vector_type(4))) short s16x4;

#define QSCALE 0.25505654708402214f   /* (1/sqrt(32)) * log2(e) */

__device__ inline short f2b(float f) {
    __hip_bfloat16 h = __float2bfloat16(f);   // HW RNE cvt
    return *reinterpret_cast<short*>(&h);
}
__device__ inline float b2f(short s) {
    union { unsigned u; float f; } v; v.u = ((unsigned)(unsigned short)s) << 16;
    return v.f;
}
__device__ inline unsigned cvt_pk(float lo, float hi) {
    unsigned r;
    asm("v_cvt_pk_bf16_f32 %0, %1, %2" : "=v"(r) : "v"(lo), "v"(hi));
    return r;
}
__device__ inline void gl_lds16(const void* g, void* l) {
    __builtin_amdgcn_global_load_lds(
        (const __attribute__((address_space(1))) void*)g,
        (__attribute__((address_space(3))) void*)l, 16, 0, 0);
}

// ---- one-shot fp32 -> bf16 weight conversion (25 matrices, zero-padded) ----
struct W2B { const float* src; short* dst; int n; int npad; };
struct W2BTab { W2B e[25]; };
__global__ void k_w2b(W2BTab tab) {
    W2B w = tab.e[blockIdx.y];
    int i = (blockIdx.x*256 + threadIdx.x) * 8;
    if (i + 8 <= w.n) {
        float4 a = *(const float4*)(w.src + i);
        float4 b = *(const float4*)(w.src + i + 4);
        short t[8] = {f2b(a.x),f2b(a.y),f2b(a.z),f2b(a.w),
                      f2b(b.x),f2b(b.y),f2b(b.z),f2b(b.w)};
        *(bf16x8*)(w.dst + i) = *(const bf16x8*)t;
    } else if (i < w.npad) {
        *(bf16x8*)(w.dst + i) = (bf16x8)0;
    }
}

// ---- stable rank == jnp.argsort: 7 blocks per batch row, noise in LDS ----
__global__ void k_rank(const float* __restrict__ noise, int* __restrict__ shuf,
                       int* __restrict__ keep_pos, float* __restrict__ out_mask)
{
    __shared__ float ns[NP];
    int b = blockIdx.x / 7, it = blockIdx.x % 7;
    const float* nr = noise + (size_t)b*NP;
    int tid = threadIdx.x;
    for (int j = tid; j < NP; j += 256) ns[j] = nr[j];
    __syncthreads();
    int i = it*256 + tid;
    if (i < NP) {
        float ni = ns[i];
        int rank = 0;
        for (int j = 0; j < NP; ++j) {
            float nj = ns[j];
            rank += (nj < ni) || (nj == ni && j < i);
        }
        shuf[b*NP + rank] = i;
        keep_pos[b*NP + i] = (rank >= NUM_MASKC) ? (rank - NUM_MASKC) : -1;
        out_mask[b*NP + i] = (rank < NUM_MASKC) ? 1.0f : 0.0f;
    }
}

// ---- xg output only ----
__global__ void k_xg(const float* __restrict__ x, float* __restrict__ out_xg)
{
    int bn = blockIdx.x;            // b*NP + n
    int b = bn / NP, n = bn % NP;
    int a0 = n / 144, r = n % 144, b0 = r / 12, c0 = r % 12;
    int t = threadIdx.x;
    if (t < PP3) {
        int pa = t / 25, rem = t % 25, pbq = rem / 5, pc = rem % 5;
        out_xg[(size_t)bn*PP3 + t] =
            x[(size_t)b*216000 + (size_t)(a0*5+pa)*3600 + (b0*5+pbq)*60 + (c0*5+pc)];
    }
}

// ---- patch extract + embed for VISIBLE tokens only (bf16 out) ----
__global__ void k_patch_vis(const float* __restrict__ x, const float* __restrict__ pw,
                            const float* __restrict__ pb, const float* __restrict__ pos,
                            const int* __restrict__ shuf, short* __restrict__ visb)
{
    int row = blockIdx.x;            // b*NKEEP + s
    int b = row / NKEEP, s = row % NKEEP;
    int n = shuf[b*NP + NUM_MASKC + s];
    int a0 = n / 144, r = n % 144, b0 = r / 12, c0 = r % 12;
    __shared__ float patch[PP3];
    int t = threadIdx.x;
    if (t < PP3) {
        int pa = t / 25, rem = t % 25, pbq = rem / 5, pc = rem % 5;
        patch[t] = x[(size_t)b*216000 + (size_t)(a0*5+pa)*3600 + (b0*5+pbq)*60 + (c0*5+pc)];
    }
    __syncthreads();
    float acc = pb[t] + pos[(size_t)n*E + t];
    const float* w = pw + (size_t)t*PP3;
    for (int k = 0; k < PP3; ++k) acc += patch[k] * w[k];
    visb[(size_t)row*E + t] = f2b(acc);
}

// ---- bf16 MFMA GEMM 64x64 (for N>=768 GEMMs), gl_lds + XOR swizzle ----
// out modes: qkvb!=null -> qkv split ; else Cb bf16.
__global__ __launch_bounds__(256) void
k_mgemm(const short* __restrict__ A, const short* __restrict__ W,
        const float* __restrict__ bias, short* __restrict__ Cb,
        int M, int N, int K, int act,
        short* __restrict__ qkvb, short* __restrict__ vTb, int S)
{
    __shared__ short As[64][64];   // 16B chunk c of row r holds global chunk c^(r&7)
    __shared__ short Ws[64][64];
    int tid = threadIdx.x;
    int lane = tid & 63, wave = tid >> 6;
    int rb = blockIdx.y * 64, cb = blockIdx.x * 64;
    int wr = (wave >> 1) * 32, wc = (wave & 1) * 32;
    int fr = lane & 15, fq = lane >> 4;
    f32x4 acc[2][2];
    #pragma unroll
    for (int m = 0; m < 2; ++m)
        #pragma unroll
        for (int n = 0; n < 2; ++n) acc[m][n] = (f32x4)0.f;
    int rl = lane >> 3, cl = lane & 7;
    int r0 = 16 * wave;
    for (int kk0 = 0; kk0 < K; kk0 += 64) {
        #pragma unroll
        for (int j = 0; j < 2; ++j) {
            int r = r0 + 8*j + rl;
            int cs = cl ^ (r & 7);
            gl_lds16(A + (size_t)(rb + r)*K + kk0 + cs*8, &As[r0 + 8*j][0]);
            gl_lds16(W + (size_t)(cb + r)*K + kk0 + cs*8, &Ws[r0 + 8*j][0]);
        }
        __syncthreads();
        #pragma unroll
        for (int t = 0; t < 2; ++t) {
            int rA0 = wr + fr, rA1 = wr + 16 + fr;
            int rB0 = wc + fr, rB1 = wc + 16 + fr;
            bf16x8 a0 = *(const bf16x8*)&As[rA0][(((4*t + fq) ^ (rA0 & 7)) << 3)];
            bf16x8 a1 = *(const bf16x8*)&As[rA1][(((4*t + fq) ^ (rA1 & 7)) << 3)];
            bf16x8 b0 = *(const bf16x8*)&Ws[rB0][(((4*t + fq) ^ (rB0 & 7)) << 3)];
            bf16x8 b1 = *(const bf16x8*)&Ws[rB1][(((4*t + fq) ^ (rB1 & 7)) << 3)];
            acc[0][0] = __builtin_amdgcn_mfma_f32_16x16x32_bf16(a0, b0, acc[0][0], 0, 0, 0);
            acc[0][1] = __builtin_amdgcn_mfma_f32_16x16x32_bf16(a0, b1, acc[0][1], 0, 0, 0);
            acc[1][0] = __builtin_amdgcn_mfma_f32_16x16x32_bf16(a1, b0, acc[1][0], 0, 0, 0);
            acc[1][1] = __builtin_amdgcn_mfma_f32_16x16x32_bf16(a1, b1, acc[1][1], 0, 0, 0);
        }
        __syncthreads();
    }
    #pragma unroll
    for (int m = 0; m < 2; ++m) {
        #pragma unroll
        for (int n = 0; n < 2; ++n) {
            int col = cb + wc + n*16 + fr;
            if (col >= N) continue;
            float bv = bias[col];
            #pragma unroll
            for (int r = 0; r < 4; ++r) {
                int row = rb + wr + m*16 + fq*4 + r;
                if (row >= M) continue;
                float v = acc[m][n][r] + bv;
                if (act == 1) v = 0.5f * v * (1.f + erff(v * 0.70710678118654752f));
                if (qkvb) {
                    if (col < 512) {
                        if (col < 256) v *= QSCALE;
                        qkvb[(size_t)row*768 + col] = f2b(v);
                    } else {
                        int b = row / S, s = row - b*S;
                        int hd = col - 512;                 // h*32 + d
                        vTb[((size_t)(b*Hh + (hd >> 5))*DH + (hd & 31))*S + s] = f2b(v);
                    }
                } else {
                    Cb[(size_t)row*N + col] = f2b(v);
                }
            }
        }
    }
}

// ---- bf16 MFMA GEMM 32x64 (for starved N<=256 GEMMs): 128 thr, 2 waves ----
// Doubles grid vs 64x64 at the same N; M % 32 == 0. Cf!=null -> fp32 out.
__global__ __launch_bounds__(128) void
k_mgemm32(const short* __restrict__ A, const short* __restrict__ W,
          const float* __restrict__ bias, float* __restrict__ Cf,
          short* __restrict__ Cb, int M, int N, int K)
{
    __shared__ short As[32][64];
    __shared__ short Ws[64][64];
    int tid = threadIdx.x;
    int lane = tid & 63, wave = tid >> 6;
    int rb = blockIdx.y * 32, cb = blockIdx.x * 64;
    int wc = wave * 32;
    int fr = lane & 15, fq = lane >> 4;
    f32x4 acc[2][2];
    #pragma unroll
    for (int m = 0; m < 2; ++m)
        #pragma unroll
        for (int n = 0; n < 2; ++n) acc[m][n] = (f32x4)0.f;
    int rl = lane >> 3, cl = lane & 7;
    for (int kk0 = 0; kk0 < K; kk0 += 64) {
        #pragma unroll
        for (int j = 0; j < 2; ++j) {            // A: stripes wave*2+j (32 rows)
            int st = (wave*2 + j)*8;
            int r = st + rl;
            int cs = cl ^ (r & 7);
            gl_lds16(A + (size_t)(rb + r)*K + kk0 + cs*8, &As[st][0]);
        }
        #pragma unroll
        for (int j = 0; j < 4; ++j) {            // W: stripes wave*4+j (64 rows)
            int st = (wave*4 + j)*8;
            int r = st + rl;
            int cs = cl ^ (r & 7);
            gl_lds16(W + (size_t)(cb + r)*K + kk0 + cs*8, &Ws[st][0]);
        }
        __syncthreads();
        #pragma unroll
        for (int t = 0; t < 2; ++t) {
            int rA0 = fr, rA1 = 16 + fr;
            int rB0 = wc + fr, rB1 = wc + 16 + fr;
            bf16x8 a0 = *(const bf16x8*)&As[rA0][(((4*t + fq) ^ (rA0 & 7)) << 3)];
            bf16x8 a1 = *(const bf16x8*)&As[rA1][(((4*t + fq) ^ (rA1 & 7)) << 3)];
            bf16x8 b0 = *(const bf16x8*)&Ws[rB0][(((4*t + fq) ^ (rB0 & 7)) << 3)];
            bf16x8 b1 = *(const bf16x8*)&Ws[rB1][(((4*t + fq) ^ (rB1 & 7)) << 3)];
            acc[0][0] = __builtin_amdgcn_mfma_f32_16x16x32_bf16(a0, b0, acc[0][0], 0, 0, 0);
            acc[0][1] = __builtin_amdgcn_mfma_f32_16x16x32_bf16(a0, b1, acc[0][1], 0, 0, 0);
            acc[1][0] = __builtin_amdgcn_mfma_f32_16x16x32_bf16(a1, b0, acc[1][0], 0, 0, 0);
            acc[1][1] = __builtin_amdgcn_mfma_f32_16x16x32_bf16(a1, b1, acc[1][1], 0, 0, 0);
        }
        __syncthreads();
    }
    #pragma unroll
    for (int m = 0; m < 2; ++m) {
        #pragma unroll
        for (int n = 0; n < 2; ++n) {
            int col = cb + wc + n*16 + fr;
            if (col >= N) continue;
            float bv = bias[col];
            #pragma unroll
            for (int r = 0; r < 4; ++r) {
                int row = rb + m*16 + fq*4 + r;
                float v = acc[m][n][r] + bv;
                if (Cf) Cf[(size_t)row*N + col] = v;
                else    Cb[(size_t)row*N + col] = f2b(v);
            }
        }
    }
}

// ---- MFMA flash attention: dbuf K/V, branch-free full tiles + tail ----
// 128 thr = 2 waves (16 q each), KBLK=64, no-max exp2 softmax (scores bounded).
__global__ __launch_bounds__(128) void
k_fattn(const short* __restrict__ qkvb, const short* __restrict__ vTb,
        short* __restrict__ o, int S)
{
    __shared__ short Ks[2][64][40];
    __shared__ short Vt[2][32][72];
    int nqt = (S + 31) >> 5;
    int bi = blockIdx.x;
    int qt = bi % nqt, bh = bi / nqt;        // bh = b*Hh + h
    int h = bh & 7, b = bh >> 3;
    int q0 = qt << 5;
    int tid = threadIdx.x;
    int lane = tid & 63, wave = tid >> 6;
    int fr = lane & 15, fq = lane >> 4;
    bf16x8 qfrag = (bf16x8)0;
    int qg = q0 + wave*16 + fr;
    if (qg < S)
        qfrag = *(const bf16x8*)(qkvb + (size_t)(b*S+qg)*768 + h*DH + 8*fq);
    f32x4 acc0 = (f32x4)0.f, acc1 = (f32x4)0.f;   // O^T rows d=4fq+r (+16), col q
    float lpart = 0.f;
    int krow = tid >> 1, kh = (tid & 1) * 16;
    int vrow = tid >> 2, vk4 = (tid & 3) * 16;
    const short* kbase = qkvb + (size_t)(b*S)*768 + 256 + h*DH + (size_t)krow*768 + kh;
    const short* vTh = vTb + (size_t)bh*DH*S + (size_t)vrow*S + vk4;
    int src1 = fr + ((fq & 1) << 5);
    int src2 = src1 + 16;
    bool sel = (fq >> 1) != 0;
    int nt = (S + 63) >> 6;
    bool tail = (S & 63) != 0;
    bf16x8 kr0, kr1, vr0, vr1;      // in-flight staging regs (T14 split)
    auto LOADF = [&](int t) {       // full tile: no bounds checks
        const short* src = kbase + (size_t)(t << 6)*768;
        kr0 = *(const bf16x8*)src;
        kr1 = *(const bf16x8*)(src + 8);
        const short* vs = vTh + (t << 6);
        vr0 = *(const bf16x8*)vs;
        vr1 = *(const bf16x8*)(vs + 8);
    };
    auto LOADT = [&](int t) {       // tail tile (encoder only)
        int kg = (t << 6) + krow;
        if (kg < S) {
            const short* src = kbase + (size_t)(t << 6)*768;
            kr0 = *(const bf16x8*)src;
            kr1 = *(const bf16x8*)(src + 8);
        } else { kr0 = (bf16x8)0; kr1 = (bf16x8)0; }
        if ((t << 6) + vk4 < S) {   // 16-chunk all-or-nothing (S % 16 == 0)
            const short* vs = vTh + (t << 6);
            vr0 = *(const bf16x8*)vs;
            vr1 = *(const bf16x8*)(vs + 8);
        } else { vr0 = (bf16x8)0; vr1 = (bf16x8)0; }
    };
    auto WRITE = [&](int p) {
        *(bf16x8*)&Ks[p][krow][kh]      = kr0;
        *(bf16x8*)&Ks[p][krow][kh + 8]  = kr1;
        *(bf16x8*)&Vt[p][vrow][vk4]     = vr0;
        *(bf16x8*)&Vt[p][vrow][vk4 + 8] = vr1;
    };
    if (tail && nt == 1) LOADT(0); else LOADF(0);
    WRITE(0);
    __syncthreads();
    for (int t = 0; t < nt; ++t) {
        int p = t & 1;
        bool masked = tail && (t == nt - 1);
        if (t + 1 < nt) {
            if (tail && (t + 1 == nt - 1)) LOADT(t + 1); else LOADF(t + 1);
        }
        f32x4 st[4];
        #pragma unroll
        for (int kt = 0; kt < 4; ++kt) {
            bf16x8 kf = *(const bf16x8*)&Ks[p][kt*16 + fr][8*fq];
            st[kt] = __builtin_amdgcn_mfma_f32_16x16x32_bf16(kf, qfrag, (f32x4)0.f, 0, 0, 0);
        }
        if (masked) {
            int kt0 = t << 6;
            #pragma unroll
            for (int kt = 0; kt < 4; ++kt)
                #pragma unroll
                for (int r = 0; r < 4; ++r)
                    if (kt0 + kt*16 + 4*fq + r >= S) st[kt][r] = -1e30f;
        }
        float tsum = 0.f;
        unsigned pk[4][2];
        #pragma unroll
        for (int kt = 0; kt < 4; ++kt) {
            float p0 = exp2f(st[kt][0]), p1 = exp2f(st[kt][1]);
            float p2 = exp2f(st[kt][2]), p3 = exp2f(st[kt][3]);
            tsum += (p0 + p1) + (p2 + p3);
            pk[kt][0] = cvt_pk(p0, p1);
            pk[kt][1] = cvt_pk(p2, p3);
        }
        lpart += tsum;
        #pragma unroll
        for (int t2 = 0; t2 < 2; ++t2) {
            unsigned a0 = __shfl(pk[2*t2][0], src1),   a1 = __shfl(pk[2*t2][1], src1);
            unsigned a2 = __shfl(pk[2*t2][0], src2),   a3 = __shfl(pk[2*t2][1], src2);
            unsigned b0 = __shfl(pk[2*t2+1][0], src1), b1 = __shfl(pk[2*t2+1][1], src1);
            unsigned b2 = __shfl(pk[2*t2+1][0], src2), b3 = __shfl(pk[2*t2+1][1], src2);
            union { unsigned u[4]; bf16x8 v; } B2;
            B2.u[0] = sel ? b0 : a0;
            B2.u[1] = sel ? b1 : a1;
            B2.u[2] = sel ? b2 : a2;
            B2.u[3] = sel ? b3 : a3;
            bf16x8 v0 = *(const bf16x8*)&Vt[p][fr][t2*32 + 8*fq];
            bf16x8 v1 = *(const bf16x8*)&Vt[p][16 + fr][t2*32 + 8*fq];
            acc0 = __builtin_amdgcn_mfma_f32_16x16x32_bf16(v0, B2.v, acc0, 0, 0, 0);
            acc1 = __builtin_amdgcn_mfma_f32_16x16x32_bf16(v1, B2.v, acc1, 0, 0, 0);
        }
        if (t + 1 < nt) WRITE(p ^ 1);         // write next tile to other buffer
        __syncthreads();
    }
    float lsum = lpart;
    lsum += __shfl_xor(lsum, 16);
    lsum += __shfl_xor(lsum, 32);
    if (qg < S) {
        float inv = 1.f / lsum;
        short* op = o + (size_t)(b*S + qg)*E + h*DH;
        s16x4 o0 = { f2b(acc0[0]*inv), f2b(acc0[1]*inv), f2b(acc0[2]*inv), f2b(acc0[3]*inv) };
        s16x4 o1 = { f2b(acc1[0]*inv), f2b(acc1[1]*inv), f2b(acc1[2]*inv), f2b(acc1[3]*inv) };
        *(s16x4*)&op[4*fq]      = o0;
        *(s16x4*)&op[16 + 4*fq] = o1;
    }
}

// ---- x = LN(x + rsd) * w + b : wave per row, bf16 I/O, no barriers ----
__global__ __launch_bounds__(256) void
k_lnadd(short* __restrict__ x, const short* __restrict__ rsd,
        const float* __restrict__ w, const float* __restrict__ bv)
{
    int row = blockIdx.x*4 + (threadIdx.x >> 6);
    int lane = threadIdx.x & 63;
    int c0 = lane * 4;
    size_t base = (size_t)row*E + c0;
    s16x4 xv = *(const s16x4*)&x[base];
    s16x4 rv = *(const s16x4*)&rsd[base];
    float v[4];
    float s = 0.f, sq = 0.f;
    #pragma unroll
    for (int j = 0; j < 4; ++j) {
        v[j] = b2f(xv[j]) + b2f(rv[j]);
        s += v[j]; sq += v[j]*v[j];
    }
    #pragma unroll
    for (int off = 1; off < 64; off <<= 1) {
        s  += __shfl_xor(s, off);
        sq += __shfl_xor(sq, off);
    }
    float mean = s * (1.f/E);
    float var = fmaxf(sq * (1.f/E) - mean*mean, 0.f);
    float rstd = 1.f / sqrtf(var + 1e-5f);
    float4 wv = *(const float4*)&w[c0];
    float4 bb = *(const float4*)&bv[c0];
    s16x4 o;
    o[0] = f2b((v[0]-mean)*rstd*wv.x + bb.x);
    o[1] = f2b((v[1]-mean)*rstd*wv.y + bb.y);
    o[2] = f2b((v[2]-mean)*rstd*wv.z + bb.z);
    o[3] = f2b((v[3]-mean)*rstd*wv.w + bb.w);
    *(s16x4*)&x[base] = o;
}

__global__ void k_mean(const short* __restrict__ xv, float* __restrict__ mb)
{
    int b = blockIdx.x, tid = threadIdx.x;
    float s = 0.f;
    for (int r = 0; r < NKEEP; ++r) s += b2f(xv[((size_t)b*NKEEP + r)*E + tid]);
    mb[b*E + tid] = s * (1.f/NKEEP);
}

__global__ void k_cls(const float* __restrict__ mb, const float* __restrict__ cw,
                      const float* __restrict__ cb, float* __restrict__ out)
{
    int t = threadIdx.x;
    if (t < Bb*NC) {
        int b = t / NC, c = t % NC;
        float acc = cb[c];
        for (int k = 0; k < E; ++k) acc += mb[b*E+k]*cw[c*E+k];
        out[t] = acc;
    }
}

// ---- scatter: xdb[b*NP+n] = (keep? enc : mask_token) + dec_pos (bf16) ----
__global__ void k_scatter(const short* __restrict__ visb, const int* __restrict__ keep_pos,
                          const float* __restrict__ mtok, const float* __restrict__ dpos,
                          short* __restrict__ xdb)
{
    int bn = blockIdx.x; int b = bn / NP, n = bn % NP;
    int t = threadIdx.x;
    int s = keep_pos[bn];
    float base = (s >= 0) ? b2f(visb[((size_t)b*NKEEP + s)*E + t]) : mtok[t];
    xdb[(size_t)bn*E + t] = f2b(base + dpos[(size_t)n*E + t]);
}

extern "C" void kernel_launch(void* const* d_in, const int* in_sizes, int n_in,
                              void* d_out, int out_size, void* d_ws, size_t ws_size,
                              hipStream_t stream)
{
    // d_in in setup_inputs() DICT order.
    const float* x        = (const float*)d_in[0];
    const float* noise    = (const float*)d_in[1];
    const float* patch_w  = (const float*)d_in[2];
    const float* patch_b  = (const float*)d_in[3];
    const float* pos      = (const float*)d_in[4];
    const float* dpos     = (const float*)d_in[5];
    const float* mtok     = (const float*)d_in[6];
    const float* pred_w   = (const float*)d_in[7];
    const float* pred_b   = (const float*)d_in[8];
    const float* cls_w    = (const float*)d_in[9];
    const float* cls_b    = (const float*)d_in[10];
    const float* enc_w[12]; for (int i = 0; i < 12; ++i) enc_w[i] = (const float*)d_in[11+i];
    const float* dec_w[12]; for (int i = 0; i < 12; ++i) dec_w[i] = (const float*)d_in[23+i];

    float* out = (float*)d_out;
    float* out_pred = out;                 // 864000
    float* out_xg   = out + 864000;        // 864000
    float* out_mask = out + 1728000;       // 6912
    float* out_cls  = out + 1734912;       // 160

    // Workspace (~49.4 MB), all-bf16 activations + bf16 weight arena.
    short* S0   = (short*)d_ws;
    short* qkvb = S0;                      // 6912*768  = 5308416
    short* bigb = qkvb + 5308416;          // 6912*1024 = 7077888 (ffn hidden)
    short* vTb  = bigb + 7077888;          // 4*8*32*1728 = 1769472
    short* visb = vTb  + 1769472;          // 1728*256  = 442368
    short* xdb  = visb + 442368;           // 6912*256  = 1769472
    short* c1b  = xdb  + 1769472;          // 1769472
    short* c2b  = c1b  + 1769472;          // 1769472
    short* wb   = c2b  + 1769472;          // 4751360 bf16 weight arena (pred padded)
    float* mb   = (float*)(wb + 4751360);  // 1024
    int* shuf   = (int*)(mb + 1024);       // 6912
    int* keep   = shuf + Bb*NP;            // 6912

    // ---- weight arena layout: per layer {qkv, out, ffn1, ffn2} ----
    const int LSTRIDE = 786432;            // 196608+65536+262144+262144
    W2BTab tab;
    int wi = 0;
    size_t off = 0;
    auto addw = [&](const float* src, int n, int npad) {
        tab.e[wi].src = src; tab.e[wi].dst = wb + off;
        tab.e[wi].n = n; tab.e[wi].npad = npad;
        ++wi; off += npad;
    };
    for (int l = 0; l < LE; ++l) {
        addw(enc_w[0] + (size_t)l*3*E*E, 3*E*E, 3*E*E);
        addw(enc_w[2] + (size_t)l*E*E,   E*E,   E*E);
        addw(enc_w[8] + (size_t)l*4*E*E, 4*E*E, 4*E*E);
        addw(enc_w[10]+ (size_t)l*4*E*E, 4*E*E, 4*E*E);
    }
    for (int l = 0; l < LD; ++l) {
        addw(dec_w[0] + (size_t)l*3*E*E, 3*E*E, 3*E*E);
        addw(dec_w[2] + (size_t)l*E*E,   E*E,   E*E);
        addw(dec_w[8] + (size_t)l*4*E*E, 4*E*E, 4*E*E);
        addw(dec_w[10]+ (size_t)l*4*E*E, 4*E*E, 4*E*E);
    }
    addw(pred_w, PP3*E, 128*E);            // pad to 128 rows (N=125 GEMM staging)
    hipLaunchKernelGGL(k_w2b, dim3(128, 25), dim3(256), 0, stream, tab);

    auto gemm = [&](const short* A, const short* W, const float* bias,
                    short* Cb, int M, int N, int K, int act,
                    short* qb, short* vb, int Sv) {
        dim3 g((N+63)/64, (M+63)/64);
        hipLaunchKernelGGL(k_mgemm, g, dim3(256), 0, stream, A, W, bias,
                           Cb, M, N, K, act, qb, vb, Sv);
    };
    auto gemm32 = [&](const short* A, const short* W, const float* bias,
                      float* Cf, short* Cb, int M, int N, int K) {
        dim3 g((N+63)/64, M/32);
        hipLaunchKernelGGL(k_mgemm32, g, dim3(128), 0, stream, A, W, bias,
                           Cf, Cb, M, N, K);
    };

    // xbuf = bf16 activations [Bl*S][E]; wbase = this stack's weight arena base
    auto layer = [&](short* xbuf, int Bl, int S, const float* const* Wp,
                     const short* wbase, int l) {
        int M = Bl * S;
        int nqt = (S + 31) / 32;
        const short* wq = wbase + (size_t)l*LSTRIDE;
        const short* wo = wq + 3*E*E;
        const short* w1 = wo + E*E;
        const short* w2 = w1 + 4*E*E;
        gemm(xbuf, wq, Wp[1] + l*3*E, nullptr, M, 3*E, E, 0, qkvb, vTb, S);
        k_fattn<<<Bl*Hh*nqt, 128, 0, stream>>>(qkvb, vTb, c1b, S);
        gemm32(c1b, wo, Wp[3] + l*E, nullptr, c2b, M, E, E);
        k_lnadd<<<M/4, 256, 0, stream>>>(xbuf, c2b, Wp[4] + l*E, Wp[5] + l*E);
        gemm(xbuf, w1, Wp[9] + l*4*E, bigb, M, 4*E, E, 1, nullptr, nullptr, 1);
        gemm32(bigb, w2, Wp[11] + l*E, nullptr, c2b, M, E, 4*E);
        k_lnadd<<<M/4, 256, 0, stream>>>(xbuf, c2b, Wp[6] + l*E, Wp[7] + l*E);
    };

    k_rank<<<Bb*7, 256, 0, stream>>>(noise, shuf, keep, out_mask);
    k_xg<<<Bb*NP, 128, 0, stream>>>(x, out_xg);
    k_patch_vis<<<Bb*NKEEP, 256, 0, stream>>>(x, patch_w, patch_b, pos, shuf, visb);

    const short* enc_wb = wb;
    const short* dec_wb = wb + (size_t)LE*LSTRIDE;
    const short* pred_wb = wb + (size_t)(LE+LD)*LSTRIDE;

    for (int l = 0; l < LE; ++l) layer(visb, Bb, NKEEP, enc_w, enc_wb, l);

    k_mean<<<Bb, 256, 0, stream>>>(visb, mb);
    k_cls<<<1, 256, 0, stream>>>(mb, cls_w, cls_b, out_cls);

    k_scatter<<<Bb*NP, 256, 0, stream>>>(visb, keep, mtok, dpos, xdb);
    for (int l = 0; l < LD; ++l) layer(xdb, Bb, NP, dec_w, dec_wb, l);
    gemm32(xdb, pred_wb, pred_b, out_pred, nullptr, Bb*NP, PP3, E);
}

// Round 22
// 531.432 us; speedup vs baseline: 1.2361x; 1.0022x over previous
//
#include <hip/hip_runtime.h>
#include <hip/hip_bf16.h>
#include <math.h>

#define E 256
#define Hh 8
#define DH 32
#define NP 1728
#define PP3 125
#define Bb 4
#define NUM_MASKC 1296
#define NKEEP 432
#define LE 4
#define LD 2
#define NC 40

typedef __attribute__((ext_vector_type(4))) float f32x4;
typedef __attribute__((ext_vector_type(8))) short bf16x8;
typedef __attribute__((ext_vector_type(4))) short s16x4;

#define QSCALE 0.25505654708402214f   /* (1/sqrt(32)) * log2(e) */

__device__ inline short f2b(float f) {
    __hip_bfloat16 h = __float2bfloat16(f);   // HW RNE cvt
    return *reinterpret_cast<short*>(&h);
}
__device__ inline float b2f(short s) {
    union { unsigned u; float f; } v; v.u = ((unsigned)(unsigned short)s) << 16;
    return v.f;
}
__device__ inline unsigned cvt_pk(float lo, float hi) {
    unsigned r;
    asm("v_cvt_pk_bf16_f32 %0, %1, %2" : "=v"(r) : "v"(lo), "v"(hi));
    return r;
}
__device__ inline void gl_lds16(const void* g, void* l) {
    __builtin_amdgcn_global_load_lds(
        (const __attribute__((address_space(1))) void*)g,
        (__attribute__((address_space(3))) void*)l, 16, 0, 0);
}

// ---- one-shot fp32 -> bf16 weight conversion (25 matrices, zero-padded) ----
struct W2B { const float* src; short* dst; int n; int npad; };
struct W2BTab { W2B e[25]; };
__global__ void k_w2b(W2BTab tab) {
    W2B w = tab.e[blockIdx.y];
    int i = (blockIdx.x*256 + threadIdx.x) * 8;
    if (i + 8 <= w.n) {
        float4 a = *(const float4*)(w.src + i);
        float4 b = *(const float4*)(w.src + i + 4);
        short t[8] = {f2b(a.x),f2b(a.y),f2b(a.z),f2b(a.w),
                      f2b(b.x),f2b(b.y),f2b(b.z),f2b(b.w)};
        *(bf16x8*)(w.dst + i) = *(const bf16x8*)t;
    } else if (i < w.npad) {
        *(bf16x8*)(w.dst + i) = (bf16x8)0;
    }
}

// ---- stable rank == jnp.argsort: 7 blocks per batch row, noise in LDS ----
__global__ void k_rank(const float* __restrict__ noise, int* __restrict__ shuf,
                       int* __restrict__ keep_pos, float* __restrict__ out_mask)
{
    __shared__ float ns[NP];
    int b = blockIdx.x / 7, it = blockIdx.x % 7;
    const float* nr = noise + (size_t)b*NP;
    int tid = threadIdx.x;
    for (int j = tid; j < NP; j += 256) ns[j] = nr[j];
    __syncthreads();
    int i = it*256 + tid;
    if (i < NP) {
        float ni = ns[i];
        int rank = 0;
        for (int j = 0; j < NP; ++j) {
            float nj = ns[j];
            rank += (nj < ni) || (nj == ni && j < i);
        }
        shuf[b*NP + rank] = i;
        keep_pos[b*NP + i] = (rank >= NUM_MASKC) ? (rank - NUM_MASKC) : -1;
        out_mask[b*NP + i] = (rank < NUM_MASKC) ? 1.0f : 0.0f;
    }
}

// ---- xg output only ----
__global__ void k_xg(const float* __restrict__ x, float* __restrict__ out_xg)
{
    int bn = blockIdx.x;            // b*NP + n
    int b = bn / NP, n = bn % NP;
    int a0 = n / 144, r = n % 144, b0 = r / 12, c0 = r % 12;
    int t = threadIdx.x;
    if (t < PP3) {
        int pa = t / 25, rem = t % 25, pbq = rem / 5, pc = rem % 5;
        out_xg[(size_t)bn*PP3 + t] =
            x[(size_t)b*216000 + (size_t)(a0*5+pa)*3600 + (b0*5+pbq)*60 + (c0*5+pc)];
    }
}

// ---- patch extract + embed for VISIBLE tokens only (bf16 out) ----
__global__ void k_patch_vis(const float* __restrict__ x, const float* __restrict__ pw,
                            const float* __restrict__ pb, const float* __restrict__ pos,
                            const int* __restrict__ shuf, short* __restrict__ visb)
{
    int row = blockIdx.x;            // b*NKEEP + s
    int b = row / NKEEP, s = row % NKEEP;
    int n = shuf[b*NP + NUM_MASKC + s];
    int a0 = n / 144, r = n % 144, b0 = r / 12, c0 = r % 12;
    __shared__ float patch[PP3];
    int t = threadIdx.x;
    if (t < PP3) {
        int pa = t / 25, rem = t % 25, pbq = rem / 5, pc = rem % 5;
        patch[t] = x[(size_t)b*216000 + (size_t)(a0*5+pa)*3600 + (b0*5+pbq)*60 + (c0*5+pc)];
    }
    __syncthreads();
    float acc = pb[t] + pos[(size_t)n*E + t];
    const float* w = pw + (size_t)t*PP3;
    for (int k = 0; k < PP3; ++k) acc += patch[k] * w[k];
    visb[(size_t)row*E + t] = f2b(acc);
}

// ---- bf16 MFMA GEMM 64x64 (large-grid GEMMs), gl_lds + XOR swizzle ----
// out modes: qkvb!=null -> qkv split ; else Cb bf16.
__global__ __launch_bounds__(256) void
k_mgemm(const short* __restrict__ A, const short* __restrict__ W,
        const float* __restrict__ bias, short* __restrict__ Cb,
        int M, int N, int K, int act,
        short* __restrict__ qkvb, short* __restrict__ vTb, int S)
{
    __shared__ short As[64][64];   // 16B chunk c of row r holds global chunk c^(r&7)
    __shared__ short Ws[64][64];
    int tid = threadIdx.x;
    int lane = tid & 63, wave = tid >> 6;
    int rb = blockIdx.y * 64, cb = blockIdx.x * 64;
    int wr = (wave >> 1) * 32, wc = (wave & 1) * 32;
    int fr = lane & 15, fq = lane >> 4;
    f32x4 acc[2][2];
    #pragma unroll
    for (int m = 0; m < 2; ++m)
        #pragma unroll
        for (int n = 0; n < 2; ++n) acc[m][n] = (f32x4)0.f;
    int rl = lane >> 3, cl = lane & 7;
    int r0 = 16 * wave;
    for (int kk0 = 0; kk0 < K; kk0 += 64) {
        #pragma unroll
        for (int j = 0; j < 2; ++j) {
            int r = r0 + 8*j + rl;
            int cs = cl ^ (r & 7);
            gl_lds16(A + (size_t)(rb + r)*K + kk0 + cs*8, &As[r0 + 8*j][0]);
            gl_lds16(W + (size_t)(cb + r)*K + kk0 + cs*8, &Ws[r0 + 8*j][0]);
        }
        __syncthreads();
        #pragma unroll
        for (int t = 0; t < 2; ++t) {
            int rA0 = wr + fr, rA1 = wr + 16 + fr;
            int rB0 = wc + fr, rB1 = wc + 16 + fr;
            bf16x8 a0 = *(const bf16x8*)&As[rA0][(((4*t + fq) ^ (rA0 & 7)) << 3)];
            bf16x8 a1 = *(const bf16x8*)&As[rA1][(((4*t + fq) ^ (rA1 & 7)) << 3)];
            bf16x8 b0 = *(const bf16x8*)&Ws[rB0][(((4*t + fq) ^ (rB0 & 7)) << 3)];
            bf16x8 b1 = *(const bf16x8*)&Ws[rB1][(((4*t + fq) ^ (rB1 & 7)) << 3)];
            acc[0][0] = __builtin_amdgcn_mfma_f32_16x16x32_bf16(a0, b0, acc[0][0], 0, 0, 0);
            acc[0][1] = __builtin_amdgcn_mfma_f32_16x16x32_bf16(a0, b1, acc[0][1], 0, 0, 0);
            acc[1][0] = __builtin_amdgcn_mfma_f32_16x16x32_bf16(a1, b0, acc[1][0], 0, 0, 0);
            acc[1][1] = __builtin_amdgcn_mfma_f32_16x16x32_bf16(a1, b1, acc[1][1], 0, 0, 0);
        }
        __syncthreads();
    }
    #pragma unroll
    for (int m = 0; m < 2; ++m) {
        #pragma unroll
        for (int n = 0; n < 2; ++n) {
            int col = cb + wc + n*16 + fr;
            if (col >= N) continue;
            float bv = bias[col];
            #pragma unroll
            for (int r = 0; r < 4; ++r) {
                int row = rb + wr + m*16 + fq*4 + r;
                if (row >= M) continue;
                float v = acc[m][n][r] + bv;
                if (act == 1) v = 0.5f * v * (1.f + erff(v * 0.70710678118654752f));
                if (qkvb) {
                    if (col < 512) {
                        if (col < 256) v *= QSCALE;
                        qkvb[(size_t)row*768 + col] = f2b(v);
                    } else {
                        int b = row / S, s = row - b*S;
                        int hd = col - 512;                 // h*32 + d
                        vTb[((size_t)(b*Hh + (hd >> 5))*DH + (hd & 31))*S + s] = f2b(v);
                    }
                } else {
                    Cb[(size_t)row*N + col] = f2b(v);
                }
            }
        }
    }
}

// ---- bf16 MFMA GEMM 32x64 (starved grids): 128 thr, 2 waves, full modes ----
// M % 32 == 0. qkvb!=null -> qkv split ; elif Cf -> fp32 ; else Cb bf16.
__global__ __launch_bounds__(128) void
k_mgemm32(const short* __restrict__ A, const short* __restrict__ W,
          const float* __restrict__ bias, float* __restrict__ Cf,
          short* __restrict__ Cb, int M, int N, int K, int act,
          short* __restrict__ qkvb, short* __restrict__ vTb, int S)
{
    __shared__ short As[32][64];
    __shared__ short Ws[64][64];
    int tid = threadIdx.x;
    int lane = tid & 63, wave = tid >> 6;
    int rb = blockIdx.y * 32, cb = blockIdx.x * 64;
    int wc = wave * 32;
    int fr = lane & 15, fq = lane >> 4;
    f32x4 acc[2][2];
    #pragma unroll
    for (int m = 0; m < 2; ++m)
        #pragma unroll
        for (int n = 0; n < 2; ++n) acc[m][n] = (f32x4)0.f;
    int rl = lane >> 3, cl = lane & 7;
    for (int kk0 = 0; kk0 < K; kk0 += 64) {
        #pragma unroll
        for (int j = 0; j < 2; ++j) {            // A: stripes wave*2+j (32 rows)
            int st = (wave*2 + j)*8;
            int r = st + rl;
            int cs = cl ^ (r & 7);
            gl_lds16(A + (size_t)(rb + r)*K + kk0 + cs*8, &As[st][0]);
        }
        #pragma unroll
        for (int j = 0; j < 4; ++j) {            // W: stripes wave*4+j (64 rows)
            int st = (wave*4 + j)*8;
            int r = st + rl;
            int cs = cl ^ (r & 7);
            gl_lds16(W + (size_t)(cb + r)*K + kk0 + cs*8, &Ws[st][0]);
        }
        __syncthreads();
        #pragma unroll
        for (int t = 0; t < 2; ++t) {
            int rA0 = fr, rA1 = 16 + fr;
            int rB0 = wc + fr, rB1 = wc + 16 + fr;
            bf16x8 a0 = *(const bf16x8*)&As[rA0][(((4*t + fq) ^ (rA0 & 7)) << 3)];
            bf16x8 a1 = *(const bf16x8*)&As[rA1][(((4*t + fq) ^ (rA1 & 7)) << 3)];
            bf16x8 b0 = *(const bf16x8*)&Ws[rB0][(((4*t + fq) ^ (rB0 & 7)) << 3)];
            bf16x8 b1 = *(const bf16x8*)&Ws[rB1][(((4*t + fq) ^ (rB1 & 7)) << 3)];
            acc[0][0] = __builtin_amdgcn_mfma_f32_16x16x32_bf16(a0, b0, acc[0][0], 0, 0, 0);
            acc[0][1] = __builtin_amdgcn_mfma_f32_16x16x32_bf16(a0, b1, acc[0][1], 0, 0, 0);
            acc[1][0] = __builtin_amdgcn_mfma_f32_16x16x32_bf16(a1, b0, acc[1][0], 0, 0, 0);
            acc[1][1] = __builtin_amdgcn_mfma_f32_16x16x32_bf16(a1, b1, acc[1][1], 0, 0, 0);
        }
        __syncthreads();
    }
    #pragma unroll
    for (int m = 0; m < 2; ++m) {
        #pragma unroll
        for (int n = 0; n < 2; ++n) {
            int col = cb + wc + n*16 + fr;
            if (col >= N) continue;
            float bv = bias[col];
            #pragma unroll
            for (int r = 0; r < 4; ++r) {
                int row = rb + m*16 + fq*4 + r;
                float v = acc[m][n][r] + bv;
                if (act == 1) v = 0.5f * v * (1.f + erff(v * 0.70710678118654752f));
                if (qkvb) {
                    if (col < 512) {
                        if (col < 256) v *= QSCALE;
                        qkvb[(size_t)row*768 + col] = f2b(v);
                    } else {
                        int b = row / S, s = row - b*S;
                        int hd = col - 512;                 // h*32 + d
                        vTb[((size_t)(b*Hh + (hd >> 5))*DH + (hd & 31))*S + s] = f2b(v);
                    }
                } else if (Cf) {
                    Cf[(size_t)row*N + col] = v;
                } else {
                    Cb[(size_t)row*N + col] = f2b(v);
                }
            }
        }
    }
}

// ---- MFMA flash attention: dbuf K/V, branch-free full tiles + tail ----
// 128 thr = 2 waves (16 q each), KBLK=64, no-max exp2 softmax (scores bounded).
__global__ __launch_bounds__(128) void
k_fattn(const short* __restrict__ qkvb, const short* __restrict__ vTb,
        short* __restrict__ o, int S)
{
    __shared__ short Ks[2][64][40];
    __shared__ short Vt[2][32][72];
    int nqt = (S + 31) >> 5;
    int bi = blockIdx.x;
    int qt = bi % nqt, bh = bi / nqt;        // bh = b*Hh + h
    int h = bh & 7, b = bh >> 3;
    int q0 = qt << 5;
    int tid = threadIdx.x;
    int lane = tid & 63, wave = tid >> 6;
    int fr = lane & 15, fq = lane >> 4;
    bf16x8 qfrag = (bf16x8)0;
    int qg = q0 + wave*16 + fr;
    if (qg < S)
        qfrag = *(const bf16x8*)(qkvb + (size_t)(b*S+qg)*768 + h*DH + 8*fq);
    f32x4 acc0 = (f32x4)0.f, acc1 = (f32x4)0.f;   // O^T rows d=4fq+r (+16), col q
    float lpart = 0.f;
    int krow = tid >> 1, kh = (tid & 1) * 16;
    int vrow = tid >> 2, vk4 = (tid & 3) * 16;
    const short* kbase = qkvb + (size_t)(b*S)*768 + 256 + h*DH + (size_t)krow*768 + kh;
    const short* vTh = vTb + (size_t)bh*DH*S + (size_t)vrow*S + vk4;
    int src1 = fr + ((fq & 1) << 5);
    int src2 = src1 + 16;
    bool sel = (fq >> 1) != 0;
    int nt = (S + 63) >> 6;
    bool tail = (S & 63) != 0;
    bf16x8 kr0, kr1, vr0, vr1;      // in-flight staging regs (T14 split)
    auto LOADF = [&](int t) {       // full tile: no bounds checks
        const short* src = kbase + (size_t)(t << 6)*768;
        kr0 = *(const bf16x8*)src;
        kr1 = *(const bf16x8*)(src + 8);
        const short* vs = vTh + (t << 6);
        vr0 = *(const bf16x8*)vs;
        vr1 = *(const bf16x8*)(vs + 8);
    };
    auto LOADT = [&](int t) {       // tail tile (encoder only)
        int kg = (t << 6) + krow;
        if (kg < S) {
            const short* src = kbase + (size_t)(t << 6)*768;
            kr0 = *(const bf16x8*)src;
            kr1 = *(const bf16x8*)(src + 8);
        } else { kr0 = (bf16x8)0; kr1 = (bf16x8)0; }
        if ((t << 6) + vk4 < S) {   // 16-chunk all-or-nothing (S % 16 == 0)
            const short* vs = vTh + (t << 6);
            vr0 = *(const bf16x8*)vs;
            vr1 = *(const bf16x8*)(vs + 8);
        } else { vr0 = (bf16x8)0; vr1 = (bf16x8)0; }
    };
    auto WRITE = [&](int p) {
        *(bf16x8*)&Ks[p][krow][kh]      = kr0;
        *(bf16x8*)&Ks[p][krow][kh + 8]  = kr1;
        *(bf16x8*)&Vt[p][vrow][vk4]     = vr0;
        *(bf16x8*)&Vt[p][vrow][vk4 + 8] = vr1;
    };
    if (tail && nt == 1) LOADT(0); else LOADF(0);
    WRITE(0);
    __syncthreads();
    for (int t = 0; t < nt; ++t) {
        int p = t & 1;
        bool masked = tail && (t == nt - 1);
        if (t + 1 < nt) {
            if (tail && (t + 1 == nt - 1)) LOADT(t + 1); else LOADF(t + 1);
        }
        f32x4 st[4];
        #pragma unroll
        for (int kt = 0; kt < 4; ++kt) {
            bf16x8 kf = *(const bf16x8*)&Ks[p][kt*16 + fr][8*fq];
            st[kt] = __builtin_amdgcn_mfma_f32_16x16x32_bf16(kf, qfrag, (f32x4)0.f, 0, 0, 0);
        }
        if (masked) {
            int kt0 = t << 6;
            #pragma unroll
            for (int kt = 0; kt < 4; ++kt)
                #pragma unroll
                for (int r = 0; r < 4; ++r)
                    if (kt0 + kt*16 + 4*fq + r >= S) st[kt][r] = -1e30f;
        }
        float tsum = 0.f;
        unsigned pk[4][2];
        #pragma unroll
        for (int kt = 0; kt < 4; ++kt) {
            float p0 = exp2f(st[kt][0]), p1 = exp2f(st[kt][1]);
            float p2 = exp2f(st[kt][2]), p3 = exp2f(st[kt][3]);
            tsum += (p0 + p1) + (p2 + p3);
            pk[kt][0] = cvt_pk(p0, p1);
            pk[kt][1] = cvt_pk(p2, p3);
        }
        lpart += tsum;
        #pragma unroll
        for (int t2 = 0; t2 < 2; ++t2) {
            unsigned a0 = __shfl(pk[2*t2][0], src1),   a1 = __shfl(pk[2*t2][1], src1);
            unsigned a2 = __shfl(pk[2*t2][0], src2),   a3 = __shfl(pk[2*t2][1], src2);
            unsigned b0 = __shfl(pk[2*t2+1][0], src1), b1 = __shfl(pk[2*t2+1][1], src1);
            unsigned b2 = __shfl(pk[2*t2+1][0], src2), b3 = __shfl(pk[2*t2+1][1], src2);
            union { unsigned u[4]; bf16x8 v; } B2;
            B2.u[0] = sel ? b0 : a0;
            B2.u[1] = sel ? b1 : a1;
            B2.u[2] = sel ? b2 : a2;
            B2.u[3] = sel ? b3 : a3;
            bf16x8 v0 = *(const bf16x8*)&Vt[p][fr][t2*32 + 8*fq];
            bf16x8 v1 = *(const bf16x8*)&Vt[p][16 + fr][t2*32 + 8*fq];
            acc0 = __builtin_amdgcn_mfma_f32_16x16x32_bf16(v0, B2.v, acc0, 0, 0, 0);
            acc1 = __builtin_amdgcn_mfma_f32_16x16x32_bf16(v1, B2.v, acc1, 0, 0, 0);
        }
        if (t + 1 < nt) WRITE(p ^ 1);         // write next tile to other buffer
        __syncthreads();
    }
    float lsum = lpart;
    lsum += __shfl_xor(lsum, 16);
    lsum += __shfl_xor(lsum, 32);
    if (qg < S) {
        float inv = 1.f / lsum;
        short* op = o + (size_t)(b*S + qg)*E + h*DH;
        s16x4 o0 = { f2b(acc0[0]*inv), f2b(acc0[1]*inv), f2b(acc0[2]*inv), f2b(acc0[3]*inv) };
        s16x4 o1 = { f2b(acc1[0]*inv), f2b(acc1[1]*inv), f2b(acc1[2]*inv), f2b(acc1[3]*inv) };
        *(s16x4*)&op[4*fq]      = o0;
        *(s16x4*)&op[16 + 4*fq] = o1;
    }
}

// ---- x = LN(x + rsd) * w + b : wave per row, bf16 I/O, no barriers ----
__global__ __launch_bounds__(256) void
k_lnadd(short* __restrict__ x, const short* __restrict__ rsd,
        const float* __restrict__ w, const float* __restrict__ bv)
{
    int row = blockIdx.x*4 + (threadIdx.x >> 6);
    int lane = threadIdx.x & 63;
    int c0 = lane * 4;
    size_t base = (size_t)row*E + c0;
    s16x4 xv = *(const s16x4*)&x[base];
    s16x4 rv = *(const s16x4*)&rsd[base];
    float v[4];
    float s = 0.f, sq = 0.f;
    #pragma unroll
    for (int j = 0; j < 4; ++j) {
        v[j] = b2f(xv[j]) + b2f(rv[j]);
        s += v[j]; sq += v[j]*v[j];
    }
    #pragma unroll
    for (int off = 1; off < 64; off <<= 1) {
        s  += __shfl_xor(s, off);
        sq += __shfl_xor(sq, off);
    }
    float mean = s * (1.f/E);
    float var = fmaxf(sq * (1.f/E) - mean*mean, 0.f);
    float rstd = 1.f / sqrtf(var + 1e-5f);
    float4 wv = *(const float4*)&w[c0];
    float4 bb = *(const float4*)&bv[c0];
    s16x4 o;
    o[0] = f2b((v[0]-mean)*rstd*wv.x + bb.x);
    o[1] = f2b((v[1]-mean)*rstd*wv.y + bb.y);
    o[2] = f2b((v[2]-mean)*rstd*wv.z + bb.z);
    o[3] = f2b((v[3]-mean)*rstd*wv.w + bb.w);
    *(s16x4*)&x[base] = o;
}

// ---- fused mean-pool + cls head: block b computes mean row + its logits ----
__global__ void k_meancls(const short* __restrict__ xv, const float* __restrict__ cw,
                          const float* __restrict__ cb, float* __restrict__ out)
{
    __shared__ float m[E];
    int b = blockIdx.x, tid = threadIdx.x;
    float s = 0.f;
    #pragma unroll 8
    for (int r = 0; r < NKEEP; ++r) s += b2f(xv[((size_t)b*NKEEP + r)*E + tid]);
    m[tid] = s * (1.f/NKEEP);
    __syncthreads();
    if (tid < NC) {
        float acc = cb[tid];
        for (int k = 0; k < E; ++k) acc += m[k]*cw[tid*E+k];
        out[b*NC + tid] = acc;
    }
}

// ---- scatter: xdb[b*NP+n] = (keep? enc : mask_token) + dec_pos (bf16) ----
__global__ void k_scatter(const short* __restrict__ visb, const int* __restrict__ keep_pos,
                          const float* __restrict__ mtok, const float* __restrict__ dpos,
                          short* __restrict__ xdb)
{
    int bn = blockIdx.x; int b = bn / NP, n = bn % NP;
    int t = threadIdx.x;
    int s = keep_pos[bn];
    float base = (s >= 0) ? b2f(visb[((size_t)b*NKEEP + s)*E + t]) : mtok[t];
    xdb[(size_t)bn*E + t] = f2b(base + dpos[(size_t)n*E + t]);
}

extern "C" void kernel_launch(void* const* d_in, const int* in_sizes, int n_in,
                              void* d_out, int out_size, void* d_ws, size_t ws_size,
                              hipStream_t stream)
{
    // d_in in setup_inputs() DICT order.
    const float* x        = (const float*)d_in[0];
    const float* noise    = (const float*)d_in[1];
    const float* patch_w  = (const float*)d_in[2];
    const float* patch_b  = (const float*)d_in[3];
    const float* pos      = (const float*)d_in[4];
    const float* dpos     = (const float*)d_in[5];
    const float* mtok     = (const float*)d_in[6];
    const float* pred_w   = (const float*)d_in[7];
    const float* pred_b   = (const float*)d_in[8];
    const float* cls_w    = (const float*)d_in[9];
    const float* cls_b    = (const float*)d_in[10];
    const float* enc_w[12]; for (int i = 0; i < 12; ++i) enc_w[i] = (const float*)d_in[11+i];
    const float* dec_w[12]; for (int i = 0; i < 12; ++i) dec_w[i] = (const float*)d_in[23+i];

    float* out = (float*)d_out;
    float* out_pred = out;                 // 864000
    float* out_xg   = out + 864000;        // 864000
    float* out_mask = out + 1728000;       // 6912
    float* out_cls  = out + 1734912;       // 160

    // Workspace (~49.4 MB), all-bf16 activations + bf16 weight arena.
    short* S0   = (short*)d_ws;
    short* qkvb = S0;                      // 6912*768  = 5308416
    short* bigb = qkvb + 5308416;          // 6912*1024 = 7077888 (ffn hidden)
    short* vTb  = bigb + 7077888;          // 4*8*32*1728 = 1769472
    short* visb = vTb  + 1769472;          // 1728*256  = 442368
    short* xdb  = visb + 442368;           // 6912*256  = 1769472
    short* c1b  = xdb  + 1769472;          // 1769472
    short* c2b  = c1b  + 1769472;          // 1769472
    short* wb   = c2b  + 1769472;          // 4751360 bf16 weight arena (pred padded)
    float* mb   = (float*)(wb + 4751360);  // 1024
    int* shuf   = (int*)(mb + 1024);       // 6912
    int* keep   = shuf + Bb*NP;            // 6912

    // ---- weight arena layout: per layer {qkv, out, ffn1, ffn2} ----
    const int LSTRIDE = 786432;            // 196608+65536+262144+262144
    W2BTab tab;
    int wi = 0;
    size_t off = 0;
    auto addw = [&](const float* src, int n, int npad) {
        tab.e[wi].src = src; tab.e[wi].dst = wb + off;
        tab.e[wi].n = n; tab.e[wi].npad = npad;
        ++wi; off += npad;
    };
    for (int l = 0; l < LE; ++l) {
        addw(enc_w[0] + (size_t)l*3*E*E, 3*E*E, 3*E*E);
        addw(enc_w[2] + (size_t)l*E*E,   E*E,   E*E);
        addw(enc_w[8] + (size_t)l*4*E*E, 4*E*E, 4*E*E);
        addw(enc_w[10]+ (size_t)l*4*E*E, 4*E*E, 4*E*E);
    }
    for (int l = 0; l < LD; ++l) {
        addw(dec_w[0] + (size_t)l*3*E*E, 3*E*E, 3*E*E);
        addw(dec_w[2] + (size_t)l*E*E,   E*E,   E*E);
        addw(dec_w[8] + (size_t)l*4*E*E, 4*E*E, 4*E*E);
        addw(dec_w[10]+ (size_t)l*4*E*E, 4*E*E, 4*E*E);
    }
    addw(pred_w, PP3*E, 128*E);            // pad to 128 rows (N=125 GEMM staging)
    hipLaunchKernelGGL(k_w2b, dim3(128, 25), dim3(256), 0, stream, tab);

    auto gemm = [&](const short* A, const short* W, const float* bias,
                    short* Cb, int M, int N, int K, int act,
                    short* qb, short* vb, int Sv) {
        dim3 g((N+63)/64, (M+63)/64);
        hipLaunchKernelGGL(k_mgemm, g, dim3(256), 0, stream, A, W, bias,
                           Cb, M, N, K, act, qb, vb, Sv);
    };
    auto gemm32 = [&](const short* A, const short* W, const float* bias,
                      float* Cf, short* Cb, int M, int N, int K, int act,
                      short* qb, short* vb, int Sv) {
        dim3 g((N+63)/64, M/32);
        hipLaunchKernelGGL(k_mgemm32, g, dim3(128), 0, stream, A, W, bias,
                           Cf, Cb, M, N, K, act, qb, vb, Sv);
    };

    // xbuf = bf16 activations [Bl*S][E]; wbase = this stack's weight arena base
    auto layer = [&](short* xbuf, int Bl, int S, const float* const* Wp,
                     const short* wbase, int l) {
        int M = Bl * S;
        bool small = (M <= 1728);          // encoder: grids starved at 64x64
        int nqt = (S + 31) / 32;
        const short* wq = wbase + (size_t)l*LSTRIDE;
        const short* wo = wq + 3*E*E;
        const short* w1 = wo + E*E;
        const short* w2 = w1 + 4*E*E;
        if (small)
            gemm32(xbuf, wq, Wp[1] + l*3*E, nullptr, nullptr, M, 3*E, E, 0, qkvb, vTb, S);
        else
            gemm(xbuf, wq, Wp[1] + l*3*E, nullptr, M, 3*E, E, 0, qkvb, vTb, S);
        k_fattn<<<Bl*Hh*nqt, 128, 0, stream>>>(qkvb, vTb, c1b, S);
        gemm32(c1b, wo, Wp[3] + l*E, nullptr, c2b, M, E, E, 0, nullptr, nullptr, 1);
        k_lnadd<<<M/4, 256, 0, stream>>>(xbuf, c2b, Wp[4] + l*E, Wp[5] + l*E);
        if (small)
            gemm32(xbuf, w1, Wp[9] + l*4*E, nullptr, bigb, M, 4*E, E, 1, nullptr, nullptr, 1);
        else
            gemm(xbuf, w1, Wp[9] + l*4*E, bigb, M, 4*E, E, 1, nullptr, nullptr, 1);
        gemm32(bigb, w2, Wp[11] + l*E, nullptr, c2b, M, E, 4*E, 0, nullptr, nullptr, 1);
        k_lnadd<<<M/4, 256, 0, stream>>>(xbuf, c2b, Wp[6] + l*E, Wp[7] + l*E);
    };

    k_rank<<<Bb*7, 256, 0, stream>>>(noise, shuf, keep, out_mask);
    k_xg<<<Bb*NP, 128, 0, stream>>>(x, out_xg);
    k_patch_vis<<<Bb*NKEEP, 256, 0, stream>>>(x, patch_w, patch_b, pos, shuf, visb);

    const short* enc_wb = wb;
    const short* dec_wb = wb + (size_t)LE*LSTRIDE;
    const short* pred_wb = wb + (size_t)(LE+LD)*LSTRIDE;

    for (int l = 0; l < LE; ++l) layer(visb, Bb, NKEEP, enc_w, enc_wb, l);

    k_meancls<<<Bb, 256, 0, stream>>>(visb, cls_w, cls_b, out_cls);

    k_scatter<<<Bb*NP, 256, 0, stream>>>(visb, keep, mtok, dpos, xdb);
    for (int l = 0; l < LD; ++l) layer(xdb, Bb, NP, dec_w, dec_wb, l);
    gemm32(xdb, pred_wb, pred_b, out_pred, nullptr, Bb*NP, PP3, E, 0, nullptr, nullptr, 1);
}